// Round 1
// baseline (1275.895 us; speedup 1.0000x reference)
//
#include <hip/hip_runtime.h>
#include <math.h>

#define NN 50000
#define EE 800000
#define ETOT (EE + NN)
#define NGR 64
#define DD 128
#define NCL 10

// ---------------- device helpers ----------------
__device__ __forceinline__ float siluf(float x){ return x / (1.f + __expf(-x)); }

// 8 KAN features of scalar x: [silu(x), B0..B6] (cubic B-splines on uniform grid
// g_j = 0.5*j - 2.5, j=0..10, Cox-de Boor, matching reference exactly in f32)
__device__ __forceinline__ void kan_feats(float x, float* f8){
  f8[0] = siluf(x);
  float b[10];
#pragma unroll
  for (int j=0;j<10;++j){
    float gj = 0.5f*j - 2.5f;
    b[j] = (x >= gj && x < gj + 0.5f) ? 1.f : 0.f;
  }
#pragma unroll
  for (int j=0;j<9;++j){              // p=1, 1/(0.5*1)=2
    float gj = 0.5f*j - 2.5f;
    b[j] = (x - gj)*2.f*b[j] + (gj + 1.0f - x)*2.f*b[j+1];
  }
#pragma unroll
  for (int j=0;j<8;++j){              // p=2, 1/(0.5*2)=1
    float gj = 0.5f*j - 2.5f;
    b[j] = (x - gj)*b[j] + (gj + 1.5f - x)*b[j+1];
  }
  const float inv3 = 2.f/3.f;         // p=3
#pragma unroll
  for (int j=0;j<7;++j){
    float gj = 0.5f*j - 2.5f;
    b[j] = (x - gj)*inv3*b[j] + (gj + 2.0f - x)*inv3*b[j+1];
  }
#pragma unroll
  for (int j=0;j<7;++j) f8[1+j] = b[j];
}

// ---------------- CSR build (dst-indexed) ----------------
__global__ void hist_kernel(const int* __restrict__ ei, int* __restrict__ deg){
  int e = blockIdx.x*256 + threadIdx.x;
  if (e >= ETOT) return;
  int dst = (e < EE) ? ei[EE + e] : (e - EE);
  atomicAdd(&deg[dst], 1);
}

__global__ void scan1_kernel(const int* __restrict__ deg, int* __restrict__ offs, int* __restrict__ part){
  __shared__ int sh[256];
  int tid = threadIdx.x;
  int i = blockIdx.x*256 + tid;
  int v = (i < NN) ? deg[i] : 0;
  sh[tid] = v; __syncthreads();
  for (int o=1;o<256;o<<=1){
    int t2 = (tid >= o) ? sh[tid - o] : 0;
    __syncthreads();
    sh[tid] += t2;
    __syncthreads();
  }
  int incl = sh[tid];
  if (i < NN) offs[i] = incl - v;          // block-local exclusive
  if (tid == 255) part[blockIdx.x] = incl; // block total
}

__global__ void scan2_kernel(int* __restrict__ part, int nb){
  __shared__ int sh[256];
  int tid = threadIdx.x;
  int v = (tid < nb) ? part[tid] : 0;
  sh[tid] = v; __syncthreads();
  for (int o=1;o<256;o<<=1){
    int t2 = (tid >= o) ? sh[tid - o] : 0;
    __syncthreads();
    sh[tid] += t2;
    __syncthreads();
  }
  if (tid < nb) part[tid] = sh[tid] - v;   // exclusive scan of block totals
}

__global__ void scan3_kernel(int* __restrict__ offs, const int* __restrict__ part, int* __restrict__ cursor){
  int i = blockIdx.x*256 + threadIdx.x;
  if (i >= NN) return;
  int o = offs[i] + part[blockIdx.x];
  offs[i] = o;
  cursor[i] = o;
}

__global__ void fill_kernel(const int* __restrict__ ei, int* __restrict__ cursor, int* __restrict__ csr){
  int e = blockIdx.x*256 + threadIdx.x;
  if (e >= ETOT) return;
  int src, dst;
  if (e < EE){ src = ei[e]; dst = ei[EE + e]; } else { src = e - EE; dst = e - EE; }
  int pos = atomicAdd(&cursor[dst], 1);
  csr[pos] = src;
}

// ---------------- fold weights: waug[l][k][o], k = i*8+f ----------------
__global__ void build_waug(const float* __restrict__ bw, const float* __restrict__ sw,
                           const float* __restrict__ sc, float* __restrict__ waug){
  int idx = blockIdx.x*256 + threadIdx.x;   // 3*1024*128
  if (idx >= 3*1024*128) return;
  int o = idx & 127;
  int k = (idx >> 7) & 1023;
  int l = idx >> 17;
  int i = k >> 3, f = k & 7;
  int oi = (l*DD + o)*DD + i;
  float w = (f == 0) ? bw[oi] : sw[oi*7 + (f-1)] * sc[oi];
  waug[idx] = w;
}

// ---------------- KANLinear as tiled f32 GEMM: M=50000, N=128, K=1024 ----------------
// block: 256 thr, TM=64 rows, TN=128 cols, BK=64 (8 input dims/stage), 16 stages
__global__ __launch_bounds__(256) void kan_gemm(const float* __restrict__ xin,
                                                const float* __restrict__ waug,
                                                float* __restrict__ hlin, int layer)
{
  __shared__ __align__(16) float As[64][68];   // [row][k local] padded
  __shared__ __align__(16) float Bs[64][128];  // [k local][out]
  const float* wl = waug + layer*(1024*128);
  const int t  = threadIdx.x;
  const int tx = t & 31, ty = t >> 5;
  const int row0 = blockIdx.x * 64;
  float acc[8][4];
#pragma unroll
  for (int a=0;a<8;++a)
#pragma unroll
    for (int b=0;b<4;++b) acc[a][b] = 0.f;

  for (int s=0;s<16;++s){
    // stage A: 512 (row, i) pairs; compute 8 KAN features each
#pragma unroll
    for (int q=0;q<2;++q){
      int p = t + q*256;
      int r = p >> 3, il = p & 7;
      int grow = row0 + r;
      float xv = (grow < NN) ? xin[grow*DD + (s*8 + il)] : 0.f;
      float f8[8];
      kan_feats(xv, f8);
      float* dstp = &As[r][il*8];
      *(float4*)(dstp)     = make_float4(f8[0],f8[1],f8[2],f8[3]);
      *(float4*)(dstp + 4) = make_float4(f8[4],f8[5],f8[6],f8[7]);
    }
    // stage B: 64x128 weight chunk
    const float* wb = wl + s*(64*128);
#pragma unroll
    for (int j=0;j<8;++j){
      int idx = j*1024 + t*4;
      *(float4*)(&Bs[idx>>7][idx&127]) = *(const float4*)(wb + idx);
    }
    __syncthreads();
#pragma unroll
    for (int k4=0;k4<64;k4+=4){
      float4 bv0 = *(float4*)(&Bs[k4+0][tx*4]);
      float4 bv1 = *(float4*)(&Bs[k4+1][tx*4]);
      float4 bv2 = *(float4*)(&Bs[k4+2][tx*4]);
      float4 bv3 = *(float4*)(&Bs[k4+3][tx*4]);
#pragma unroll
      for (int rr=0;rr<8;++rr){
        float4 av = *(float4*)(&As[ty*8+rr][k4]);
        acc[rr][0] = fmaf(av.x, bv0.x, acc[rr][0]);
        acc[rr][1] = fmaf(av.x, bv0.y, acc[rr][1]);
        acc[rr][2] = fmaf(av.x, bv0.z, acc[rr][2]);
        acc[rr][3] = fmaf(av.x, bv0.w, acc[rr][3]);
        acc[rr][0] = fmaf(av.y, bv1.x, acc[rr][0]);
        acc[rr][1] = fmaf(av.y, bv1.y, acc[rr][1]);
        acc[rr][2] = fmaf(av.y, bv1.z, acc[rr][2]);
        acc[rr][3] = fmaf(av.y, bv1.w, acc[rr][3]);
        acc[rr][0] = fmaf(av.z, bv2.x, acc[rr][0]);
        acc[rr][1] = fmaf(av.z, bv2.y, acc[rr][1]);
        acc[rr][2] = fmaf(av.z, bv2.z, acc[rr][2]);
        acc[rr][3] = fmaf(av.z, bv2.w, acc[rr][3]);
        acc[rr][0] = fmaf(av.w, bv3.x, acc[rr][0]);
        acc[rr][1] = fmaf(av.w, bv3.y, acc[rr][1]);
        acc[rr][2] = fmaf(av.w, bv3.z, acc[rr][2]);
        acc[rr][3] = fmaf(av.w, bv3.w, acc[rr][3]);
      }
    }
    __syncthreads();
  }
#pragma unroll
  for (int rr=0;rr<8;++rr){
    int grow = row0 + ty*8 + rr;
    if (grow < NN)
      *(float4*)(&hlin[grow*DD + tx*4]) = make_float4(acc[rr][0],acc[rr][1],acc[rr][2],acc[rr][3]);
  }
}

// ---------------- attention logits a_src/a_dst per (node, head) ----------------
__global__ __launch_bounds__(256) void attlog_kernel(const float* __restrict__ hlin,
    const float* __restrict__ attS, const float* __restrict__ attD,
    float* __restrict__ asrc, float* __restrict__ adst, int layer)
{
  int t = blockIdx.x*256 + threadIdx.x;
  if (t >= NN*4) return;
  int n = t >> 2, h = t & 3;
  const float4* hp = (const float4*)(hlin + n*DD + h*32);
  const float4* ws = (const float4*)(attS + (layer*4 + h)*32);
  const float4* wd = (const float4*)(attD + (layer*4 + h)*32);
  float ss = 0.f, sd = 0.f;
#pragma unroll
  for (int j=0;j<8;++j){
    float4 hv = hp[j]; float4 a = ws[j]; float4 b = wd[j];
    ss += hv.x*a.x + hv.y*a.y + hv.z*a.z + hv.w*a.w;
    sd += hv.x*b.x + hv.y*b.y + hv.z*b.z + hv.w*b.w;
  }
  asrc[t] = ss; adst[t] = sd;
}

// ---------------- GAT aggregation: 1 wave per dst node, gather via CSR ----------------
__global__ __launch_bounds__(256) void attn_kernel(
    const float* __restrict__ hlin, const float* __restrict__ asrc, const float* __restrict__ adst,
    const int* __restrict__ offs, const int* __restrict__ deg, const int* __restrict__ csr,
    const float* __restrict__ bias, float* __restrict__ hout, int layer)
{
  const int wave = threadIdx.x >> 6;
  const int lane = threadIdx.x & 63;
  const int n = blockIdx.x*4 + wave;
  if (n >= NN) return;
  const int st = offs[n];
  const int d  = deg[n];
  const float4 ad = *(const float4*)(adst + n*4);

  // pass 1: per-head max of leaky_relu(a_src[s]+a_dst[n])
  float m0=-3.4e38f, m1=-3.4e38f, m2=-3.4e38f, m3=-3.4e38f;
  for (int e=lane; e<d; e+=64){
    int s = csr[st+e];
    float4 a4 = *(const float4*)(asrc + s*4);
    float e0=a4.x+ad.x; e0=(e0>0.f)?e0:0.2f*e0;
    float e1=a4.y+ad.y; e1=(e1>0.f)?e1:0.2f*e1;
    float e2=a4.z+ad.z; e2=(e2>0.f)?e2:0.2f*e2;
    float e3=a4.w+ad.w; e3=(e3>0.f)?e3:0.2f*e3;
    m0=fmaxf(m0,e0); m1=fmaxf(m1,e1); m2=fmaxf(m2,e2); m3=fmaxf(m3,e3);
  }
#pragma unroll
  for (int o=1;o<64;o<<=1){
    m0=fmaxf(m0,__shfl_xor(m0,o)); m1=fmaxf(m1,__shfl_xor(m1,o));
    m2=fmaxf(m2,__shfl_xor(m2,o)); m3=fmaxf(m3,__shfl_xor(m3,o));
  }
  // pass 2: per-head softmax denominator
  float s0=0.f,s1=0.f,s2=0.f,s3=0.f;
  for (int e=lane; e<d; e+=64){
    int s = csr[st+e];
    float4 a4 = *(const float4*)(asrc + s*4);
    float e0=a4.x+ad.x; e0=(e0>0.f)?e0:0.2f*e0;
    float e1=a4.y+ad.y; e1=(e1>0.f)?e1:0.2f*e1;
    float e2=a4.z+ad.z; e2=(e2>0.f)?e2:0.2f*e2;
    float e3=a4.w+ad.w; e3=(e3>0.f)?e3:0.2f*e3;
    s0 += __expf(e0-m0); s1 += __expf(e1-m1);
    s2 += __expf(e2-m2); s3 += __expf(e3-m3);
  }
#pragma unroll
  for (int o=1;o<64;o<<=1){
    s0+=__shfl_xor(s0,o); s1+=__shfl_xor(s1,o);
    s2+=__shfl_xor(s2,o); s3+=__shfl_xor(s3,o);
  }
  float i0=1.f/(s0+1e-16f), i1=1.f/(s1+1e-16f), i2=1.f/(s2+1e-16f), i3=1.f/(s3+1e-16f);

  // pass 3: channel-parallel weighted gather (lane -> channels lane, lane+64)
  const int c0 = lane, c1 = lane + 64;
  const int h0 = lane >> 5;                 // head of c0 (0/1); head of c1 is h0+2
  const float adA = h0 ? ad.y : ad.x;
  const float adB = h0 ? ad.w : ad.z;
  const float mA  = h0 ? m1 : m0;
  const float mB  = h0 ? m3 : m2;
  const float iA  = h0 ? i1 : i0;
  const float iB  = h0 ? i3 : i2;
  float acc0 = 0.f, acc1 = 0.f;
  for (int e=0;e<d;++e){
    int s = csr[st+e];
    float aS = asrc[s*4 + h0];
    float bS = asrc[s*4 + 2 + h0];
    float eA = aS + adA; eA = (eA>0.f)?eA:0.2f*eA;
    float eB = bS + adB; eB = (eB>0.f)?eB:0.2f*eB;
    float alA = __expf(eA - mA) * iA;
    float alB = __expf(eB - mB) * iB;
    const float* hr = hlin + (long)s*DD;
    acc0 = fmaf(alA, hr[c0], acc0);
    acc1 = fmaf(alB, hr[c1], acc1);
  }
  float o0 = siluf(acc0 + bias[layer*DD + c0]);
  float o1 = siluf(acc1 + bias[layer*DD + c1]);
  hout[n*DD + c0] = o0;
  hout[n*DD + c1] = o1;
}

// ---------------- global_add_pool (batch is sorted) ----------------
__global__ __launch_bounds__(128) void pool_kernel(const float* __restrict__ h,
    const int* __restrict__ batch, float* __restrict__ pooled)
{
  int c = threadIdx.x;                 // channel 0..127
  int n0 = blockIdx.x*128;
  float sum = 0.f; int cur = -1;
  for (int r=0;r<128;++r){
    int n = n0 + r;
    if (n >= NN) break;
    int g = batch[n];
    if (g != cur){
      if (cur >= 0) atomicAdd(&pooled[cur*DD + c], sum);
      cur = g; sum = 0.f;
    }
    sum += h[n*DD + c];
  }
  if (cur >= 0) atomicAdd(&pooled[cur*DD + c], sum);
}

// ---------------- KAN readout + log_softmax (1 block per graph) ----------------
__global__ __launch_bounds__(64) void readout_kernel(const float* __restrict__ pooled,
    const float* __restrict__ bw, const float* __restrict__ sw, const float* __restrict__ sc,
    float* __restrict__ out)
{
  int g = blockIdx.x, lane = threadIdx.x;
  float xa = pooled[g*DD + lane];
  float xb = pooled[g*DD + lane + 64];
  float fa[8], fb[8];
  kan_feats(xa, fa);
  kan_feats(xb, fb);
  float logits[NCL];
#pragma unroll
  for (int c=0;c<NCL;++c){
    int ia = c*DD + lane, ib = ia + 64;
    float sca = sc[ia], scb = sc[ib];
    float p = fa[0]*bw[ia] + fb[0]*bw[ib];
#pragma unroll
    for (int f=1;f<8;++f)
      p += fa[f]*sw[ia*7 + f-1]*sca + fb[f]*sw[ib*7 + f-1]*scb;
#pragma unroll
    for (int o=1;o<64;o<<=1) p += __shfl_xor(p, o);
    logits[c] = p;
  }
  float mx = logits[0];
#pragma unroll
  for (int c=1;c<NCL;++c) mx = fmaxf(mx, logits[c]);
  float lse = 0.f;
#pragma unroll
  for (int c=0;c<NCL;++c) lse += __expf(logits[c]-mx);
  lse = mx + logf(lse);
  if (lane < NCL){
    float v = 0.f;
#pragma unroll
    for (int c=0;c<NCL;++c) if (lane == c) v = logits[c] - lse;
    out[g*NCL + lane] = v;
  }
}

// ---------------- host ----------------
extern "C" void kernel_launch(void* const* d_in, const int* in_sizes, int n_in,
                              void* d_out, int out_size, void* d_ws, size_t ws_size,
                              hipStream_t stream)
{
  const float* x        = (const float*)d_in[0];
  const int*   ei       = (const int*)  d_in[1];
  const int*   batch    = (const int*)  d_in[2];
  const float* base_w   = (const float*)d_in[3];
  const float* spline_w = (const float*)d_in[4];
  const float* scaler   = (const float*)d_in[5];
  const float* att_src  = (const float*)d_in[6];
  const float* att_dst  = (const float*)d_in[7];
  const float* bias     = (const float*)d_in[8];
  const float* ro_bw    = (const float*)d_in[9];
  const float* ro_sw    = (const float*)d_in[10];
  const float* ro_sc    = (const float*)d_in[11];
  float* out = (float*)d_out;

  char* p = (char*)d_ws;
  auto alloc = [&](size_t bytes)->char* {
    char* r = p;
    p += (bytes + 255) & ~(size_t)255;
    return r;
  };
  float* hlin   = (float*)alloc((size_t)NN*DD*4);
  float* hbuf   = (float*)alloc((size_t)NN*DD*4);
  float* waug   = (float*)alloc((size_t)3*1024*128*4);
  float* asrc   = (float*)alloc((size_t)NN*4*4);
  float* adst   = (float*)alloc((size_t)NN*4*4);
  float* pooled = (float*)alloc((size_t)NGR*DD*4);
  int*   deg    = (int*)alloc((size_t)NN*4);
  int*   offs   = (int*)alloc((size_t)NN*4);
  int*   cursor = (int*)alloc((size_t)NN*4);
  int*   csr    = (int*)alloc((size_t)ETOT*4);
  int*   part   = (int*)alloc((size_t)256*4);

  const int nbs = (NN + 255)/256;             // 196 scan blocks
  hipMemsetAsync(deg, 0, (size_t)NN*sizeof(int), stream);
  hist_kernel <<<(ETOT+255)/256, 256, 0, stream>>>(ei, deg);
  scan1_kernel<<<nbs, 256, 0, stream>>>(deg, offs, part);
  scan2_kernel<<<1,   256, 0, stream>>>(part, nbs);
  scan3_kernel<<<nbs, 256, 0, stream>>>(offs, part, cursor);
  fill_kernel <<<(ETOT+255)/256, 256, 0, stream>>>(ei, cursor, csr);
  build_waug  <<<(3*1024*128)/256, 256, 0, stream>>>(base_w, spline_w, scaler, waug);

  const float* cur = x;
  for (int l=0; l<3; ++l){
    kan_gemm     <<<(NN+63)/64,    256, 0, stream>>>(cur, waug, hlin, l);
    attlog_kernel<<<(NN*4+255)/256,256, 0, stream>>>(hlin, att_src, att_dst, asrc, adst, l);
    attn_kernel  <<<(NN+3)/4,      256, 0, stream>>>(hlin, asrc, adst, offs, deg, csr, bias, hbuf, l);
    cur = hbuf;
  }
  hipMemsetAsync(pooled, 0, (size_t)NGR*DD*sizeof(float), stream);
  pool_kernel   <<<(NN+127)/128, 128, 0, stream>>>(hbuf, batch, pooled);
  readout_kernel<<<NGR, 64, 0, stream>>>(pooled, ro_bw, ro_sw, ro_sc, out);
}

// Round 2
// 857.641 us; speedup vs baseline: 1.4877x; 1.4877x over previous
//
#include <hip/hip_runtime.h>
#include <math.h>

#define NN 50000
#define EE 800000
#define ETOT (EE + NN)
#define NGR 64
#define DD 128
#define NCL 10

typedef __attribute__((ext_vector_type(16))) float float16_t;
typedef __attribute__((ext_vector_type(8)))  __bf16 bf16x8;

// ---------------- device helpers ----------------
__device__ __forceinline__ float siluf(float x){ return x / (1.f + __expf(-x)); }

__device__ __forceinline__ unsigned short f2bf(float f){
  union { float f; unsigned u; } v; v.f = f;
  unsigned r = v.u + 0x7fffu + ((v.u >> 16) & 1u);
  return (unsigned short)(r >> 16);
}

// 8 KAN features of scalar x: [silu(x), B0..B6].
// Uniform cubic B-spline closed form: knots g_j = 0.5j-2.5; u=2x+5, cell=floor(u),
// nonzero bases j=cell-3..cell with values M4(t+k). Verified vs Cox-de Boor.
__device__ __forceinline__ void kan_feats(float x, float* f8){
  f8[0] = siluf(x);
  float u = 2.f*x + 5.f;
  int cell = -1;
  float n0=0.f,n1=0.f,n2=0.f,n3=0.f;
  if (u >= 0.f && u < 10.f){
    cell = (int)u;
    float t = u - (float)cell;
    float t2 = t*t, t3 = t2*t;
    float omt = 1.f - t;
    const float s6 = 1.f/6.f;
    n0 = t3*s6;                                  // j == cell
    n1 = s6*(1.f + 3.f*t + 3.f*t2 - 3.f*t3);     // j == cell-1
    n2 = s6*(4.f - 6.f*t2 + 3.f*t3);             // j == cell-2
    n3 = omt*omt*omt*s6;                         // j == cell-3
  }
#pragma unroll
  for (int j=0;j<7;++j){
    int k = cell - j;
    float v = (k==0)?n0:((k==1)?n1:((k==2)?n2:((k==3)?n3:0.f)));
    f8[1+j] = v;
  }
}

// ---------------- CSR build (dst-indexed) ----------------
__global__ void hist_kernel(const int* __restrict__ ei, int* __restrict__ deg){
  int e = blockIdx.x*256 + threadIdx.x;
  if (e >= ETOT) return;
  int dst = (e < EE) ? ei[EE + e] : (e - EE);
  atomicAdd(&deg[dst], 1);
}

__global__ void scan1_kernel(const int* __restrict__ deg, int* __restrict__ offs, int* __restrict__ part){
  __shared__ int sh[256];
  int tid = threadIdx.x;
  int i = blockIdx.x*256 + tid;
  int v = (i < NN) ? deg[i] : 0;
  sh[tid] = v; __syncthreads();
  for (int o=1;o<256;o<<=1){
    int t2 = (tid >= o) ? sh[tid - o] : 0;
    __syncthreads();
    sh[tid] += t2;
    __syncthreads();
  }
  int incl = sh[tid];
  if (i < NN) offs[i] = incl - v;
  if (tid == 255) part[blockIdx.x] = incl;
}

__global__ void scan2_kernel(int* __restrict__ part, int nb){
  __shared__ int sh[256];
  int tid = threadIdx.x;
  int v = (tid < nb) ? part[tid] : 0;
  sh[tid] = v; __syncthreads();
  for (int o=1;o<256;o<<=1){
    int t2 = (tid >= o) ? sh[tid - o] : 0;
    __syncthreads();
    sh[tid] += t2;
    __syncthreads();
  }
  if (tid < nb) part[tid] = sh[tid] - v;
}

__global__ void scan3_kernel(int* __restrict__ offs, const int* __restrict__ part, int* __restrict__ cursor){
  int i = blockIdx.x*256 + threadIdx.x;
  if (i >= NN) return;
  int o = offs[i] + part[blockIdx.x];
  offs[i] = o;
  cursor[i] = o;
}

__global__ void fill_kernel(const int* __restrict__ ei, int* __restrict__ cursor, int* __restrict__ csr){
  int e = blockIdx.x*256 + threadIdx.x;
  if (e >= ETOT) return;
  int src, dst;
  if (e < EE){ src = ei[e]; dst = ei[EE + e]; } else { src = e - EE; dst = e - EE; }
  int pos = atomicAdd(&cursor[dst], 1);
  csr[pos] = src;
}

// ---------------- fold weights into bf16, MFMA-fragment order ----------------
// Fragment order per layer, per stage s (K-chunk of 64):
//   elem(ntile, sl, half, n, j) at (((ntile*4+sl)*64) + half*32 + n)*8 + j
// where k = s*64 + sl*16 + half*8 + j, o = ntile*32 + n.
__global__ void build_wfrag(const float* __restrict__ bw, const float* __restrict__ sw,
                            const float* __restrict__ sc, unsigned short* __restrict__ wfrag){
  int idx = blockIdx.x*256 + threadIdx.x;   // (l, o, k)
  if (idx >= 3*128*1024) return;
  int k = idx & 1023;
  int o = (idx >> 10) & 127;
  int l = idx >> 17;
  int i = k >> 3, f = k & 7;
  int oi = (l*DD + o)*DD + i;
  float w = (f == 0) ? bw[oi] : sw[oi*7 + (f-1)] * sc[oi];
  int s = k >> 6;
  int sl = (k >> 4) & 3, half = (k >> 3) & 1, j = k & 7;
  int ntile = o >> 5, n = o & 31;
  int dst = l*131072 + s*8192 + (((ntile*4 + sl)*64) + half*32 + n)*8 + j;
  wfrag[dst] = f2bf(w);
}

// ---------------- KANLinear via bf16 MFMA: M=50000, N=128, K=1024 ----------------
// Block 256 thr = 4 waves; tile 128 rows x 128 cols; wave tile 64x64 (4 MFMA tiles).
// K staged 64 at a time; A features computed in-kernel, packed per-lane fragment.
__global__ __launch_bounds__(256) void kan_gemm(const float* __restrict__ xin,
                                                const unsigned short* __restrict__ wfrag,
                                                float* __restrict__ hlin, int layer)
{
  __shared__ __align__(16) unsigned short As2[8192];  // 16 KB, fragment order
  __shared__ __align__(16) unsigned short Bs2[8192];  // 16 KB
  const int t    = threadIdx.x;
  const int lane = t & 63;
  const int w    = t >> 6;
  const int wm   = w & 1;          // A half (rows wm*64..)
  const int wn   = w >> 1;         // B half (cols wn*64..)
  const int half = lane >> 5;
  const int mn   = lane & 31;
  const int row0 = blockIdx.x * 128;
  const unsigned short* wl = wfrag + layer*131072;

  float16_t acc00, acc01, acc10, acc11;
#pragma unroll
  for (int i=0;i<16;++i){ acc00[i]=0.f; acc01[i]=0.f; acc10[i]=0.f; acc11[i]=0.f; }

  for (int s=0; s<16; ++s){
    // ---- stage A: 512 (row, i2) pairs; each thread does 2 pairs = 4 scalars ----
#pragma unroll
    for (int q=0;q<2;++q){
      int p = q*256 + t;            // 0..511
      int row = p & 127;
      int i2  = p >> 7;             // dim pair 0..3
      int grow = row0 + row;
      float2 xv = (grow < NN) ? *(const float2*)(xin + grow*DD + s*8 + i2*2)
                              : make_float2(0.f, 0.f);
      int mtile = row >> 5, m = row & 31;
#pragma unroll
      for (int e=0;e<2;++e){
        float xs = e ? xv.y : xv.x;
        int sl = i2, hf = e;        // i_local = i2*2+e = sl*2+half
        float f8[8];
        kan_feats(xs, f8);
        union { unsigned short us[8]; int4 i4; } pk;
#pragma unroll
        for (int j=0;j<8;++j) pk.us[j] = f2bf(f8[j]);
        int fi = ((mtile*4 + sl)*64 + hf*32 + m);
        *(int4*)(As2 + fi*8) = pk.i4;
      }
    }
    // ---- stage B: contiguous 16 KB copy of pre-swizzled weights ----
    const unsigned short* wsrc = wl + s*8192;
#pragma unroll
    for (int q=0;q<4;++q){
      int eo = q*2048 + t*8;
      *(int4*)(Bs2 + eo) = *(const int4*)(wsrc + eo);
    }
    __syncthreads();
    // ---- compute: 4 k16-steps ----
#pragma unroll
    for (int sl=0; sl<4; ++sl){
      int4 ai0 = *(const int4*)(As2 + (((wm*2+0)*4 + sl)*64 + lane)*8);
      int4 ai1 = *(const int4*)(As2 + (((wm*2+1)*4 + sl)*64 + lane)*8);
      int4 bi0 = *(const int4*)(Bs2 + (((wn*2+0)*4 + sl)*64 + lane)*8);
      int4 bi1 = *(const int4*)(Bs2 + (((wn*2+1)*4 + sl)*64 + lane)*8);
      bf16x8 a0 = __builtin_bit_cast(bf16x8, ai0);
      bf16x8 a1 = __builtin_bit_cast(bf16x8, ai1);
      bf16x8 b0 = __builtin_bit_cast(bf16x8, bi0);
      bf16x8 b1 = __builtin_bit_cast(bf16x8, bi1);
      acc00 = __builtin_amdgcn_mfma_f32_32x32x16_bf16(a0, b0, acc00, 0, 0, 0);
      acc01 = __builtin_amdgcn_mfma_f32_32x32x16_bf16(a0, b1, acc01, 0, 0, 0);
      acc10 = __builtin_amdgcn_mfma_f32_32x32x16_bf16(a1, b0, acc10, 0, 0, 0);
      acc11 = __builtin_amdgcn_mfma_f32_32x32x16_bf16(a1, b1, acc11, 0, 0, 0);
    }
    __syncthreads();
  }

  // ---- epilogue: C/D layout col=lane&31, row=(reg&3)+8*(reg>>2)+4*(lane>>5) ----
#pragma unroll
  for (int mt=0; mt<2; ++mt){
#pragma unroll
    for (int nt=0; nt<2; ++nt){
      const float16_t* a = (mt==0) ? ((nt==0)? &acc00 : &acc01)
                                   : ((nt==0)? &acc10 : &acc11);
#pragma unroll
      for (int reg=0; reg<16; ++reg){
        int r = (reg&3) + 8*(reg>>2) + 4*half;
        int row = row0 + (wm*2+mt)*32 + r;
        int col = (wn*2+nt)*32 + mn;
        if (row < NN) hlin[row*DD + col] = (*a)[reg];
      }
    }
  }
}

// ---------------- attention logits a_src/a_dst per (node, head) ----------------
__global__ __launch_bounds__(256) void attlog_kernel(const float* __restrict__ hlin,
    const float* __restrict__ attS, const float* __restrict__ attD,
    float* __restrict__ asrc, float* __restrict__ adst, int layer)
{
  int t = blockIdx.x*256 + threadIdx.x;
  if (t >= NN*4) return;
  int n = t >> 2, h = t & 3;
  const float4* hp = (const float4*)(hlin + n*DD + h*32);
  const float4* ws = (const float4*)(attS + (layer*4 + h)*32);
  const float4* wd = (const float4*)(attD + (layer*4 + h)*32);
  float ss = 0.f, sd = 0.f;
#pragma unroll
  for (int j=0;j<8;++j){
    float4 hv = hp[j]; float4 a = ws[j]; float4 b = wd[j];
    ss += hv.x*a.x + hv.y*a.y + hv.z*a.z + hv.w*a.w;
    sd += hv.x*b.x + hv.y*b.y + hv.z*b.z + hv.w*b.w;
  }
  asrc[t] = ss; adst[t] = sd;
}

// ---------------- GAT aggregation: 1 wave per dst node, gather via CSR ----------------
__global__ __launch_bounds__(256) void attn_kernel(
    const float* __restrict__ hlin, const float* __restrict__ asrc, const float* __restrict__ adst,
    const int* __restrict__ offs, const int* __restrict__ deg, const int* __restrict__ csr,
    const float* __restrict__ bias, float* __restrict__ hout, int layer)
{
  const int wave = threadIdx.x >> 6;
  const int lane = threadIdx.x & 63;
  const int n = blockIdx.x*4 + wave;
  if (n >= NN) return;
  const int st = offs[n];
  const int d  = deg[n];
  const float4 ad = *(const float4*)(adst + n*4);

  float m0=-3.4e38f, m1=-3.4e38f, m2=-3.4e38f, m3=-3.4e38f;
  for (int e=lane; e<d; e+=64){
    int s = csr[st+e];
    float4 a4 = *(const float4*)(asrc + s*4);
    float e0=a4.x+ad.x; e0=(e0>0.f)?e0:0.2f*e0;
    float e1=a4.y+ad.y; e1=(e1>0.f)?e1:0.2f*e1;
    float e2=a4.z+ad.z; e2=(e2>0.f)?e2:0.2f*e2;
    float e3=a4.w+ad.w; e3=(e3>0.f)?e3:0.2f*e3;
    m0=fmaxf(m0,e0); m1=fmaxf(m1,e1); m2=fmaxf(m2,e2); m3=fmaxf(m3,e3);
  }
#pragma unroll
  for (int o=1;o<64;o<<=1){
    m0=fmaxf(m0,__shfl_xor(m0,o)); m1=fmaxf(m1,__shfl_xor(m1,o));
    m2=fmaxf(m2,__shfl_xor(m2,o)); m3=fmaxf(m3,__shfl_xor(m3,o));
  }
  float s0=0.f,s1=0.f,s2=0.f,s3=0.f;
  for (int e=lane; e<d; e+=64){
    int s = csr[st+e];
    float4 a4 = *(const float4*)(asrc + s*4);
    float e0=a4.x+ad.x; e0=(e0>0.f)?e0:0.2f*e0;
    float e1=a4.y+ad.y; e1=(e1>0.f)?e1:0.2f*e1;
    float e2=a4.z+ad.z; e2=(e2>0.f)?e2:0.2f*e2;
    float e3=a4.w+ad.w; e3=(e3>0.f)?e3:0.2f*e3;
    s0 += __expf(e0-m0); s1 += __expf(e1-m1);
    s2 += __expf(e2-m2); s3 += __expf(e3-m3);
  }
#pragma unroll
  for (int o=1;o<64;o<<=1){
    s0+=__shfl_xor(s0,o); s1+=__shfl_xor(s1,o);
    s2+=__shfl_xor(s2,o); s3+=__shfl_xor(s3,o);
  }
  float i0=1.f/(s0+1e-16f), i1=1.f/(s1+1e-16f), i2=1.f/(s2+1e-16f), i3=1.f/(s3+1e-16f);

  const int c0 = lane, c1 = lane + 64;
  const int h0 = lane >> 5;
  const float adA = h0 ? ad.y : ad.x;
  const float adB = h0 ? ad.w : ad.z;
  const float mA  = h0 ? m1 : m0;
  const float mB  = h0 ? m3 : m2;
  const float iA  = h0 ? i1 : i0;
  const float iB  = h0 ? i3 : i2;
  float acc0 = 0.f, acc1 = 0.f;
  for (int e=0;e<d;++e){
    int s = csr[st+e];
    float aS = asrc[s*4 + h0];
    float bS = asrc[s*4 + 2 + h0];
    float eA = aS + adA; eA = (eA>0.f)?eA:0.2f*eA;
    float eB = bS + adB; eB = (eB>0.f)?eB:0.2f*eB;
    float alA = __expf(eA - mA) * iA;
    float alB = __expf(eB - mB) * iB;
    const float* hr = hlin + (long)s*DD;
    acc0 = fmaf(alA, hr[c0], acc0);
    acc1 = fmaf(alB, hr[c1], acc1);
  }
  float o0 = siluf(acc0 + bias[layer*DD + c0]);
  float o1 = siluf(acc1 + bias[layer*DD + c1]);
  hout[n*DD + c0] = o0;
  hout[n*DD + c1] = o1;
}

// ---------------- global_add_pool (batch is sorted) ----------------
__global__ __launch_bounds__(128) void pool_kernel(const float* __restrict__ h,
    const int* __restrict__ batch, float* __restrict__ pooled)
{
  int c = threadIdx.x;
  int n0 = blockIdx.x*128;
  float sum = 0.f; int cur = -1;
  for (int r=0;r<128;++r){
    int n = n0 + r;
    if (n >= NN) break;
    int g = batch[n];
    if (g != cur){
      if (cur >= 0) atomicAdd(&pooled[cur*DD + c], sum);
      cur = g; sum = 0.f;
    }
    sum += h[n*DD + c];
  }
  if (cur >= 0) atomicAdd(&pooled[cur*DD + c], sum);
}

// ---------------- KAN readout + log_softmax (1 block per graph) ----------------
__global__ __launch_bounds__(64) void readout_kernel(const float* __restrict__ pooled,
    const float* __restrict__ bw, const float* __restrict__ sw, const float* __restrict__ sc,
    float* __restrict__ out)
{
  int g = blockIdx.x, lane = threadIdx.x;
  float xa = pooled[g*DD + lane];
  float xb = pooled[g*DD + lane + 64];
  float fa[8], fb[8];
  kan_feats(xa, fa);
  kan_feats(xb, fb);
  float logits[NCL];
#pragma unroll
  for (int c=0;c<NCL;++c){
    int ia = c*DD + lane, ib = ia + 64;
    float sca = sc[ia], scb = sc[ib];
    float p = fa[0]*bw[ia] + fb[0]*bw[ib];
#pragma unroll
    for (int f=1;f<8;++f)
      p += fa[f]*sw[ia*7 + f-1]*sca + fb[f]*sw[ib*7 + f-1]*scb;
#pragma unroll
    for (int o=1;o<64;o<<=1) p += __shfl_xor(p, o);
    logits[c] = p;
  }
  float mx = logits[0];
#pragma unroll
  for (int c=1;c<NCL;++c) mx = fmaxf(mx, logits[c]);
  float lse = 0.f;
#pragma unroll
  for (int c=0;c<NCL;++c) lse += __expf(logits[c]-mx);
  lse = mx + logf(lse);
  if (lane < NCL){
    float v = 0.f;
#pragma unroll
    for (int c=0;c<NCL;++c) if (lane == c) v = logits[c] - lse;
    out[g*NCL + lane] = v;
  }
}

// ---------------- host ----------------
extern "C" void kernel_launch(void* const* d_in, const int* in_sizes, int n_in,
                              void* d_out, int out_size, void* d_ws, size_t ws_size,
                              hipStream_t stream)
{
  const float* x        = (const float*)d_in[0];
  const int*   ei       = (const int*)  d_in[1];
  const int*   batch    = (const int*)  d_in[2];
  const float* base_w   = (const float*)d_in[3];
  const float* spline_w = (const float*)d_in[4];
  const float* scaler   = (const float*)d_in[5];
  const float* att_src  = (const float*)d_in[6];
  const float* att_dst  = (const float*)d_in[7];
  const float* bias     = (const float*)d_in[8];
  const float* ro_bw    = (const float*)d_in[9];
  const float* ro_sw    = (const float*)d_in[10];
  const float* ro_sc    = (const float*)d_in[11];
  float* out = (float*)d_out;

  char* p = (char*)d_ws;
  auto alloc = [&](size_t bytes)->char* {
    char* r = p;
    p += (bytes + 255) & ~(size_t)255;
    return r;
  };
  float* hlin   = (float*)alloc((size_t)NN*DD*4);
  float* hbuf   = (float*)alloc((size_t)NN*DD*4);
  unsigned short* wfrag = (unsigned short*)alloc((size_t)3*131072*2);
  float* asrc   = (float*)alloc((size_t)NN*4*4);
  float* adst   = (float*)alloc((size_t)NN*4*4);
  float* pooled = (float*)alloc((size_t)NGR*DD*4);
  int*   deg    = (int*)alloc((size_t)NN*4);
  int*   offs   = (int*)alloc((size_t)NN*4);
  int*   cursor = (int*)alloc((size_t)NN*4);
  int*   csr    = (int*)alloc((size_t)ETOT*4);
  int*   part   = (int*)alloc((size_t)256*4);

  const int nbs = (NN + 255)/256;
  hipMemsetAsync(deg, 0, (size_t)NN*sizeof(int), stream);
  hist_kernel <<<(ETOT+255)/256, 256, 0, stream>>>(ei, deg);
  scan1_kernel<<<nbs, 256, 0, stream>>>(deg, offs, part);
  scan2_kernel<<<1,   256, 0, stream>>>(part, nbs);
  scan3_kernel<<<nbs, 256, 0, stream>>>(offs, part, cursor);
  fill_kernel <<<(ETOT+255)/256, 256, 0, stream>>>(ei, cursor, csr);
  build_wfrag <<<(3*128*1024)/256, 256, 0, stream>>>(base_w, spline_w, scaler, wfrag);

  const float* cur = x;
  for (int l=0; l<3; ++l){
    kan_gemm     <<<(NN+127)/128,  256, 0, stream>>>(cur, wfrag, hlin, l);
    attlog_kernel<<<(NN*4+255)/256,256, 0, stream>>>(hlin, att_src, att_dst, asrc, adst, l);
    attn_kernel  <<<(NN+3)/4,      256, 0, stream>>>(hlin, asrc, adst, offs, deg, csr, bias, hbuf, l);
    cur = hbuf;
  }
  hipMemsetAsync(pooled, 0, (size_t)NGR*DD*sizeof(float), stream);
  pool_kernel   <<<(NN+127)/128, 128, 0, stream>>>(hbuf, batch, pooled);
  readout_kernel<<<NGR, 64, 0, stream>>>(pooled, ro_bw, ro_sw, ro_sc, out);
}

// Round 3
// 808.102 us; speedup vs baseline: 1.5789x; 1.0613x over previous
//
#include <hip/hip_runtime.h>
#include <math.h>

#define NN 50000
#define EE 800000
#define ETOT (EE + NN)
#define NGR 64
#define DD 128
#define NCL 10

typedef __attribute__((ext_vector_type(16))) float float16_t;
typedef __attribute__((ext_vector_type(8)))  __bf16 bf16x8;

// ---------------- device helpers ----------------
__device__ __forceinline__ float siluf(float x){ return x / (1.f + __expf(-x)); }

__device__ __forceinline__ unsigned short f2bf(float f){
  union { float f; unsigned u; } v; v.f = f;
  unsigned r = v.u + 0x7fffu + ((v.u >> 16) & 1u);
  return (unsigned short)(r >> 16);
}

// 8 KAN features of scalar x: [silu(x), B0..B6] (closed-form uniform cubic B-spline)
__device__ __forceinline__ void kan_feats(float x, float* f8){
  f8[0] = siluf(x);
  float u = 2.f*x + 5.f;
  int cell = -1;
  float n0=0.f,n1=0.f,n2=0.f,n3=0.f;
  if (u >= 0.f && u < 10.f){
    cell = (int)u;
    float t = u - (float)cell;
    float t2 = t*t, t3 = t2*t;
    float omt = 1.f - t;
    const float s6 = 1.f/6.f;
    n0 = t3*s6;
    n1 = s6*(1.f + 3.f*t + 3.f*t2 - 3.f*t3);
    n2 = s6*(4.f - 6.f*t2 + 3.f*t3);
    n3 = omt*omt*omt*s6;
  }
#pragma unroll
  for (int j=0;j<7;++j){
    int k = cell - j;
    float v = (k==0)?n0:((k==1)?n1:((k==2)?n2:((k==3)?n3:0.f)));
    f8[1+j] = v;
  }
}

// ---------------- CSR build (dst-indexed) ----------------
__global__ void hist_kernel(const int* __restrict__ ei, int* __restrict__ deg){
  int e = blockIdx.x*256 + threadIdx.x;
  if (e >= ETOT) return;
  int dst = (e < EE) ? ei[EE + e] : (e - EE);
  atomicAdd(&deg[dst], 1);
}

__global__ void scan1_kernel(const int* __restrict__ deg, int* __restrict__ offs, int* __restrict__ part){
  __shared__ int sh[256];
  int tid = threadIdx.x;
  int i = blockIdx.x*256 + tid;
  int v = (i < NN) ? deg[i] : 0;
  sh[tid] = v; __syncthreads();
  for (int o=1;o<256;o<<=1){
    int t2 = (tid >= o) ? sh[tid - o] : 0;
    __syncthreads();
    sh[tid] += t2;
    __syncthreads();
  }
  int incl = sh[tid];
  if (i < NN) offs[i] = incl - v;
  if (tid == 255) part[blockIdx.x] = incl;
}

__global__ void scan2_kernel(int* __restrict__ part, int nb){
  __shared__ int sh[256];
  int tid = threadIdx.x;
  int v = (tid < nb) ? part[tid] : 0;
  sh[tid] = v; __syncthreads();
  for (int o=1;o<256;o<<=1){
    int t2 = (tid >= o) ? sh[tid - o] : 0;
    __syncthreads();
    sh[tid] += t2;
    __syncthreads();
  }
  if (tid < nb) part[tid] = sh[tid] - v;
}

__global__ void scan3_kernel(int* __restrict__ offs, const int* __restrict__ part, int* __restrict__ cursor){
  int i = blockIdx.x*256 + threadIdx.x;
  if (i >= NN) return;
  int o = offs[i] + part[blockIdx.x];
  offs[i] = o;
  cursor[i] = o;
}

__global__ void fill_kernel(const int* __restrict__ ei, int* __restrict__ cursor, int* __restrict__ csr){
  int e = blockIdx.x*256 + threadIdx.x;
  if (e >= ETOT) return;
  int src, dst;
  if (e < EE){ src = ei[e]; dst = ei[EE + e]; } else { src = e - EE; dst = e - EE; }
  int pos = atomicAdd(&cursor[dst], 1);
  csr[pos] = src;
}

// ---------------- fold weights into bf16, MFMA-fragment order ----------------
__global__ void build_wfrag(const float* __restrict__ bw, const float* __restrict__ sw,
                            const float* __restrict__ sc, unsigned short* __restrict__ wfrag){
  int idx = blockIdx.x*256 + threadIdx.x;
  if (idx >= 3*128*1024) return;
  int k = idx & 1023;
  int o = (idx >> 10) & 127;
  int l = idx >> 17;
  int i = k >> 3, f = k & 7;
  int oi = (l*DD + o)*DD + i;
  float w = (f == 0) ? bw[oi] : sw[oi*7 + (f-1)] * sc[oi];
  int s = k >> 6;
  int sl = (k >> 4) & 3, half = (k >> 3) & 1, j = k & 7;
  int ntile = o >> 5, n = o & 31;
  int dst = l*131072 + s*8192 + (((ntile*4 + sl)*64) + half*32 + n)*8 + j;
  wfrag[dst] = f2bf(w);
}

// ---------------- KANLinear via bf16 MFMA, A-fragments computed in registers ----------------
// Key fact: one 32x32x16 A-fragment (8 bf16 of lane) == kan_feats of the single
// scalar x[row0+wm*32+(lane&31)][i], i = s*8 + sl*2 + (lane>>5). No LDS for A.
// Block 256 = 4 waves; tile 64 rows x 128 cols; wave tile 32x64 (2 MFMA tiles).
// B double-buffered in LDS; one barrier per K-stage of 64.
__global__ __launch_bounds__(256) void kan_gemm(const float* __restrict__ xin,
                                                const unsigned short* __restrict__ wfrag,
                                                float* __restrict__ hlin, int layer)
{
  __shared__ __align__(16) unsigned short Bs[2][8192];
  const int t    = threadIdx.x;
  const int lane = t & 63;
  const int w    = t >> 6;
  const int wm   = w & 1;          // row half (32 rows)
  const int wn   = w >> 1;         // col half (64 cols)
  const int half = lane >> 5;
  const int mn   = lane & 31;
  const int row0 = blockIdx.x * 64;
  const unsigned short* wl = wfrag + layer*131072;

  const int rowA = row0 + wm*32 + mn;
  const float* xr = xin + (size_t)((rowA < NN) ? rowA : 0)*DD + half;

  float16_t acc0, acc1;
#pragma unroll
  for (int i=0;i<16;++i){ acc0[i]=0.f; acc1[i]=0.f; }

  // prologue: stage B for s=0, prefetch x for s=0
#pragma unroll
  for (int q=0;q<4;++q){
    int eo = q*2048 + t*8;
    *(int4*)(&Bs[0][eo]) = *(const int4*)(wl + eo);
  }
  float xv0 = xr[0], xv1 = xr[2], xv2 = xr[4], xv3 = xr[6];

  for (int s=0; s<16; ++s){
    __syncthreads();
    float xn0=0.f, xn1=0.f, xn2=0.f, xn3=0.f;
    if (s < 15){
      const unsigned short* wsrc = wl + (s+1)*8192;
#pragma unroll
      for (int q=0;q<4;++q){
        int eo = q*2048 + t*8;
        *(int4*)(&Bs[(s+1)&1][eo]) = *(const int4*)(wsrc + eo);
      }
      const float* xp = xr + (s+1)*8;
      xn0 = xp[0]; xn1 = xp[2]; xn2 = xp[4]; xn3 = xp[6];
    }
    const unsigned short* B = Bs[s&1];
#pragma unroll
    for (int sl=0; sl<4; ++sl){
      float xs = (sl==0)?xv0:((sl==1)?xv1:((sl==2)?xv2:xv3));
      float f8[8];
      kan_feats(xs, f8);
      union { unsigned short us[8]; int4 i4; } pk;
#pragma unroll
      for (int j=0;j<8;++j) pk.us[j] = f2bf(f8[j]);
      bf16x8 a = __builtin_bit_cast(bf16x8, pk.i4);
      int4 b0i = *(const int4*)(B + (((wn*2+0)*4 + sl)*64 + lane)*8);
      int4 b1i = *(const int4*)(B + (((wn*2+1)*4 + sl)*64 + lane)*8);
      acc0 = __builtin_amdgcn_mfma_f32_32x32x16_bf16(a, __builtin_bit_cast(bf16x8, b0i), acc0, 0, 0, 0);
      acc1 = __builtin_amdgcn_mfma_f32_32x32x16_bf16(a, __builtin_bit_cast(bf16x8, b1i), acc1, 0, 0, 0);
    }
    xv0=xn0; xv1=xn1; xv2=xn2; xv3=xn3;
  }

  // epilogue: C/D layout col=lane&31, row=(reg&3)+8*(reg>>2)+4*(lane>>5)
#pragma unroll
  for (int nt=0; nt<2; ++nt){
    const float16_t* a = nt ? &acc1 : &acc0;
#pragma unroll
    for (int reg=0; reg<16; ++reg){
      int r = (reg&3) + 8*(reg>>2) + 4*half;
      int row = row0 + wm*32 + r;
      int col = wn*64 + nt*32 + mn;
      if (row < NN) hlin[row*DD + col] = (*a)[reg];
    }
  }
}

// ---------------- attention logits a_src/a_dst per (node, head) ----------------
__global__ __launch_bounds__(256) void attlog_kernel(const float* __restrict__ hlin,
    const float* __restrict__ attS, const float* __restrict__ attD,
    float* __restrict__ asrc, float* __restrict__ adst, int layer)
{
  int t = blockIdx.x*256 + threadIdx.x;
  if (t >= NN*4) return;
  int n = t >> 2, h = t & 3;
  const float4* hp = (const float4*)(hlin + n*DD + h*32);
  const float4* ws = (const float4*)(attS + (layer*4 + h)*32);
  const float4* wd = (const float4*)(attD + (layer*4 + h)*32);
  float ss = 0.f, sd = 0.f;
#pragma unroll
  for (int j=0;j<8;++j){
    float4 hv = hp[j]; float4 a = ws[j]; float4 b = wd[j];
    ss += hv.x*a.x + hv.y*a.y + hv.z*a.z + hv.w*a.w;
    sd += hv.x*b.x + hv.y*b.y + hv.z*b.z + hv.w*b.w;
  }
  asrc[t] = ss; adst[t] = sd;
}

// ---------------- GAT aggregation v2: (edge,head)-parallel softmax, shuffle-broadcast ----------------
// One wave per dst node. lane = eL*4 + h (16 edges x 4 heads per chunk).
// Channel pass: lane covers channels (lane, lane+64); alpha/src via __shfl broadcast.
__global__ __launch_bounds__(256) void attn_kernel(
    const float* __restrict__ hlin, const float* __restrict__ asrc, const float* __restrict__ adst,
    const int* __restrict__ offs, const int* __restrict__ deg, const int* __restrict__ csr,
    const float* __restrict__ bias, float* __restrict__ hout, int layer)
{
  const int wave = threadIdx.x >> 6;
  const int lane = threadIdx.x & 63;
  const int n = blockIdx.x*4 + wave;
  if (n >= NN) return;
  const int st = offs[n];
  const int d  = deg[n];
  const int eL = lane >> 2, h = lane & 3;
  const float adh = adst[n*4 + h];

  // chunk 0 cached in registers
  int sI = 0; float ev = -3.4e38f;
  const bool val0 = (eL < d);
  if (val0){
    sI = csr[st + eL];
    float av = asrc[sI*4 + h];
    float e0 = av + adh;
    ev = (e0 > 0.f) ? e0 : 0.2f*e0;
  }
  // pass 1: max
  float mL = ev;
  for (int c=16; c<d; c+=16){
    int e = c + eL;
    if (e < d){
      int s2 = csr[st + e];
      float av = asrc[s2*4 + h];
      float e0 = av + adh;
      float evv = (e0 > 0.f) ? e0 : 0.2f*e0;
      mL = fmaxf(mL, evv);
    }
  }
#pragma unroll
  for (int o=4;o<64;o<<=1) mL = fmaxf(mL, __shfl_xor(mL, o));
  // pass 2: sum
  float a0 = val0 ? __expf(ev - mL) : 0.f;
  float sL = a0;
  for (int c=16; c<d; c+=16){
    int e = c + eL;
    if (e < d){
      int s2 = csr[st + e];
      float av = asrc[s2*4 + h];
      float e0 = av + adh;
      float evv = (e0 > 0.f) ? e0 : 0.2f*e0;
      sL += __expf(evv - mL);
    }
  }
#pragma unroll
  for (int o=4;o<64;o<<=1) sL += __shfl_xor(sL, o);
  const float inv = 1.f/(sL + 1e-16f);

  // pass 3: channel gather with shuffle-broadcast alphas
  const int hc0 = lane >> 5;
  float acc0 = 0.f, acc1 = 0.f;
  {
    float al = a0 * inv;
    int lim = (d < 16) ? d : 16;
    for (int j=0;j<lim;++j){
      int srcj = __shfl(sI, j*4);
      float aA = __shfl(al, j*4 + hc0);
      float aB = __shfl(al, j*4 + 2 + hc0);
      const float* hr = hlin + (size_t)srcj*DD;
      acc0 = fmaf(aA, hr[lane],      acc0);
      acc1 = fmaf(aB, hr[lane + 64], acc1);
    }
  }
  for (int c=16; c<d; c+=16){
    int e = c + eL;
    int s2 = 0; float al = 0.f;
    if (e < d){
      s2 = csr[st + e];
      float av = asrc[s2*4 + h];
      float e0 = av + adh;
      float evv = (e0 > 0.f) ? e0 : 0.2f*e0;
      al = __expf(evv - mL) * inv;
    }
    int lim = ((d - c) < 16) ? (d - c) : 16;
    for (int j=0;j<lim;++j){
      int srcj = __shfl(s2, j*4);
      float aA = __shfl(al, j*4 + hc0);
      float aB = __shfl(al, j*4 + 2 + hc0);
      const float* hr = hlin + (size_t)srcj*DD;
      acc0 = fmaf(aA, hr[lane],      acc0);
      acc1 = fmaf(aB, hr[lane + 64], acc1);
    }
  }
  float o0 = siluf(acc0 + bias[layer*DD + lane]);
  float o1 = siluf(acc1 + bias[layer*DD + lane + 64]);
  hout[n*DD + lane]      = o0;
  hout[n*DD + lane + 64] = o1;
}

// ---------------- global_add_pool (batch is sorted) ----------------
__global__ __launch_bounds__(128) void pool_kernel(const float* __restrict__ h,
    const int* __restrict__ batch, float* __restrict__ pooled)
{
  int c = threadIdx.x;
  int n0 = blockIdx.x*128;
  float sum = 0.f; int cur = -1;
  for (int r=0;r<128;++r){
    int n = n0 + r;
    if (n >= NN) break;
    int g = batch[n];
    if (g != cur){
      if (cur >= 0) atomicAdd(&pooled[cur*DD + c], sum);
      cur = g; sum = 0.f;
    }
    sum += h[n*DD + c];
  }
  if (cur >= 0) atomicAdd(&pooled[cur*DD + c], sum);
}

// ---------------- KAN readout + log_softmax (1 block per graph) ----------------
__global__ __launch_bounds__(64) void readout_kernel(const float* __restrict__ pooled,
    const float* __restrict__ bw, const float* __restrict__ sw, const float* __restrict__ sc,
    float* __restrict__ out)
{
  int g = blockIdx.x, lane = threadIdx.x;
  float xa = pooled[g*DD + lane];
  float xb = pooled[g*DD + lane + 64];
  float fa[8], fb[8];
  kan_feats(xa, fa);
  kan_feats(xb, fb);
  float logits[NCL];
#pragma unroll
  for (int c=0;c<NCL;++c){
    int ia = c*DD + lane, ib = ia + 64;
    float sca = sc[ia], scb = sc[ib];
    float p = fa[0]*bw[ia] + fb[0]*bw[ib];
#pragma unroll
    for (int f=1;f<8;++f)
      p += fa[f]*sw[ia*7 + f-1]*sca + fb[f]*sw[ib*7 + f-1]*scb;
#pragma unroll
    for (int o=1;o<64;o<<=1) p += __shfl_xor(p, o);
    logits[c] = p;
  }
  float mx = logits[0];
#pragma unroll
  for (int c=1;c<NCL;++c) mx = fmaxf(mx, logits[c]);
  float lse = 0.f;
#pragma unroll
  for (int c=0;c<NCL;++c) lse += __expf(logits[c]-mx);
  lse = mx + logf(lse);
  if (lane < NCL){
    float v = 0.f;
#pragma unroll
    for (int c=0;c<NCL;++c) if (lane == c) v = logits[c] - lse;
    out[g*NCL + lane] = v;
  }
}

// ---------------- host ----------------
extern "C" void kernel_launch(void* const* d_in, const int* in_sizes, int n_in,
                              void* d_out, int out_size, void* d_ws, size_t ws_size,
                              hipStream_t stream)
{
  const float* x        = (const float*)d_in[0];
  const int*   ei       = (const int*)  d_in[1];
  const int*   batch    = (const int*)  d_in[2];
  const float* base_w   = (const float*)d_in[3];
  const float* spline_w = (const float*)d_in[4];
  const float* scaler   = (const float*)d_in[5];
  const float* att_src  = (const float*)d_in[6];
  const float* att_dst  = (const float*)d_in[7];
  const float* bias     = (const float*)d_in[8];
  const float* ro_bw    = (const float*)d_in[9];
  const float* ro_sw    = (const float*)d_in[10];
  const float* ro_sc    = (const float*)d_in[11];
  float* out = (float*)d_out;

  char* p = (char*)d_ws;
  auto alloc = [&](size_t bytes)->char* {
    char* r = p;
    p += (bytes + 255) & ~(size_t)255;
    return r;
  };
  float* hlin   = (float*)alloc((size_t)NN*DD*4);
  float* hbuf   = (float*)alloc((size_t)NN*DD*4);
  unsigned short* wfrag = (unsigned short*)alloc((size_t)3*131072*2);
  float* asrc   = (float*)alloc((size_t)NN*4*4);
  float* adst   = (float*)alloc((size_t)NN*4*4);
  float* pooled = (float*)alloc((size_t)NGR*DD*4);
  int*   deg    = (int*)alloc((size_t)NN*4);
  int*   offs   = (int*)alloc((size_t)NN*4);
  int*   cursor = (int*)alloc((size_t)NN*4);
  int*   csr    = (int*)alloc((size_t)ETOT*4);
  int*   part   = (int*)alloc((size_t)256*4);

  const int nbs = (NN + 255)/256;
  hipMemsetAsync(deg, 0, (size_t)NN*sizeof(int), stream);
  hist_kernel <<<(ETOT+255)/256, 256, 0, stream>>>(ei, deg);
  scan1_kernel<<<nbs, 256, 0, stream>>>(deg, offs, part);
  scan2_kernel<<<1,   256, 0, stream>>>(part, nbs);
  scan3_kernel<<<nbs, 256, 0, stream>>>(offs, part, cursor);
  fill_kernel <<<(ETOT+255)/256, 256, 0, stream>>>(ei, cursor, csr);
  build_wfrag <<<(3*128*1024)/256, 256, 0, stream>>>(base_w, spline_w, scaler, wfrag);

  const float* cur = x;
  for (int l=0; l<3; ++l){
    kan_gemm     <<<(NN+63)/64,    256, 0, stream>>>(cur, wfrag, hlin, l);
    attlog_kernel<<<(NN*4+255)/256,256, 0, stream>>>(hlin, att_src, att_dst, asrc, adst, l);
    attn_kernel  <<<(NN+3)/4,      256, 0, stream>>>(hlin, asrc, adst, offs, deg, csr, bias, hbuf, l);
    cur = hbuf;
  }
  hipMemsetAsync(pooled, 0, (size_t)NGR*DD*sizeof(float), stream);
  pool_kernel   <<<(NN+127)/128, 128, 0, stream>>>(hbuf, batch, pooled);
  readout_kernel<<<NGR, 64, 0, stream>>>(pooled, ro_bw, ro_sw, ro_sc, out);
}

// Round 4
// 652.428 us; speedup vs baseline: 1.9556x; 1.2386x over previous
//
#include <hip/hip_runtime.h>
#include <math.h>

#define NN 50000
#define EE 800000
#define ETOT (EE + NN)
#define NGR 64
#define DD 128
#define NCL 10

typedef __attribute__((ext_vector_type(16))) float float16_t;
typedef __attribute__((ext_vector_type(8)))  __bf16 bf16x8;

// ---------------- device helpers ----------------
__device__ __forceinline__ float siluf(float x){ return x / (1.f + __expf(-x)); }

__device__ __forceinline__ unsigned f2bf(float f){
  union { float f; unsigned u; } v; v.f = f;
  unsigned r = v.u + 0x7fffu + ((v.u >> 16) & 1u);
  return (r >> 16) & 0xffffu;
}

// 8 KAN features of scalar x: [silu(x), B0..B6] (float version for readout)
__device__ __forceinline__ void kan_feats(float x, float* f8){
  f8[0] = siluf(x);
  float u = 2.f*x + 5.f;
  int cell = -1;
  float n0=0.f,n1=0.f,n2=0.f,n3=0.f;
  if (u >= 0.f && u < 10.f){
    cell = (int)u;
    float t = u - (float)cell;
    float t2 = t*t, t3 = t2*t;
    float omt = 1.f - t;
    const float s6 = 1.f/6.f;
    n0 = t3*s6;
    n1 = s6*(1.f + 3.f*t + 3.f*t2 - 3.f*t3);
    n2 = s6*(4.f - 6.f*t2 + 3.f*t3);
    n3 = omt*omt*omt*s6;
  }
#pragma unroll
  for (int j=0;j<7;++j){
    int k = cell - j;
    float v = (k==0)?n0:((k==1)?n1:((k==2)?n2:((k==3)?n3:0.f)));
    f8[1+j] = v;
  }
}

// Packed bf16 A-fragment of scalar x: us[0..7] = [silu, B0..B6, ...].
// Bases built via 64-bit shift: P = [n3,n2,n1,n0] in 16-bit lanes, placed at
// slot (cell-3). ~2x fewer VALU than the 7-way select loop.
__device__ __forceinline__ int4 kan_feats_pack(float x){
  unsigned sbf = f2bf(siluf(x));
  float u = 2.f*x + 5.f;
  bool valid = (u >= 0.f) && (u < 10.f);
  float uc = valid ? u : 0.f;
  int cell = (int)uc;
  float t = uc - (float)cell;
  float t2 = t*t, t3 = t2*t, omt = 1.f - t;
  const float s6 = 1.f/6.f;
  float n0 = t3*s6;
  float n1 = s6*(1.f + 3.f*t + 3.f*t2 - 3.f*t3);
  float n2 = s6*(4.f - 6.f*t2 + 3.f*t3);
  float n3 = omt*omt*omt*s6;
  unsigned p0=f2bf(n0), p1=f2bf(n1), p2=f2bf(n2), p3=f2bf(n3);
  unsigned long long P = ((unsigned long long)(p1 | (p0<<16)) << 32)
                       |  (unsigned long long)(p3 | (p2<<16));
  int sh = cell*16 - 48;
  unsigned long long shl    = P << (sh & 63);
  unsigned long long shrhi  = P >> ((64 - sh) & 63);
  unsigned long long shllo2 = P << ((sh - 64) & 63);
  unsigned long long shrlo  = P >> ((-sh) & 63);
  unsigned long long F0, F1;
  if (sh < 0)       { F0 = shrlo; F1 = 0ull; }
  else if (sh < 64) { F0 = shl;   F1 = (sh==0)? 0ull : shrhi; }
  else              { F0 = 0ull;  F1 = shllo2; }
  if (!valid){ F0 = 0ull; F1 = 0ull; }
  unsigned w0 = ((unsigned)(F0 & 0xffffull) << 16) | sbf;
  unsigned w1 = (unsigned)((F0 >> 16) & 0xffffffffull);
  unsigned w2 = (unsigned)((F0 >> 48) & 0xffffull) | (((unsigned)(F1 & 0xffffull)) << 16);
  unsigned w3 = (unsigned)((F1 >> 16) & 0xffffffffull);
  return make_int4((int)w0,(int)w1,(int)w2,(int)w3);
}

// ---------------- CSR build (dst-indexed) ----------------
__global__ void hist_kernel(const int* __restrict__ ei, int* __restrict__ deg){
  int e = blockIdx.x*256 + threadIdx.x;
  if (e >= ETOT) return;
  int dst = (e < EE) ? ei[EE + e] : (e - EE);
  atomicAdd(&deg[dst], 1);
}

__global__ void scan1_kernel(const int* __restrict__ deg, int* __restrict__ offs, int* __restrict__ part){
  __shared__ int sh[256];
  int tid = threadIdx.x;
  int i = blockIdx.x*256 + tid;
  int v = (i < NN) ? deg[i] : 0;
  sh[tid] = v; __syncthreads();
  for (int o=1;o<256;o<<=1){
    int t2 = (tid >= o) ? sh[tid - o] : 0;
    __syncthreads();
    sh[tid] += t2;
    __syncthreads();
  }
  int incl = sh[tid];
  if (i < NN) offs[i] = incl - v;
  if (tid == 255) part[blockIdx.x] = incl;
}

__global__ void scan2_kernel(int* __restrict__ part, int nb){
  __shared__ int sh[256];
  int tid = threadIdx.x;
  int v = (tid < nb) ? part[tid] : 0;
  sh[tid] = v; __syncthreads();
  for (int o=1;o<256;o<<=1){
    int t2 = (tid >= o) ? sh[tid - o] : 0;
    __syncthreads();
    sh[tid] += t2;
    __syncthreads();
  }
  if (tid < nb) part[tid] = sh[tid] - v;
}

__global__ void scan3_kernel(int* __restrict__ offs, const int* __restrict__ part, int* __restrict__ cursor){
  int i = blockIdx.x*256 + threadIdx.x;
  if (i >= NN) return;
  int o = offs[i] + part[blockIdx.x];
  offs[i] = o;
  cursor[i] = o;
}

__global__ void fill_kernel(const int* __restrict__ ei, int* __restrict__ cursor, int* __restrict__ csr){
  int e = blockIdx.x*256 + threadIdx.x;
  if (e >= ETOT) return;
  int src, dst;
  if (e < EE){ src = ei[e]; dst = ei[EE + e]; } else { src = e - EE; dst = e - EE; }
  int pos = atomicAdd(&cursor[dst], 1);
  csr[pos] = src;
}

// ---------------- fold weights into bf16, MFMA-fragment order ----------------
__global__ void build_wfrag(const float* __restrict__ bw, const float* __restrict__ sw,
                            const float* __restrict__ sc, unsigned short* __restrict__ wfrag){
  int idx = blockIdx.x*256 + threadIdx.x;
  if (idx >= 3*128*1024) return;
  int k = idx & 1023;
  int o = (idx >> 10) & 127;
  int l = idx >> 17;
  int i = k >> 3, f = k & 7;
  int oi = (l*DD + o)*DD + i;
  float w = (f == 0) ? bw[oi] : sw[oi*7 + (f-1)] * sc[oi];
  int s = k >> 6;
  int sl = (k >> 4) & 3, half = (k >> 3) & 1, j = k & 7;
  int ntile = o >> 5, n = o & 31;
  int dst = l*131072 + s*8192 + (((ntile*4 + sl)*64) + half*32 + n)*8 + j;
  wfrag[dst] = (unsigned short)f2bf(w);
}

// ---------------- feats: x -> bf16 A-fragments in global (fragment order) ----------------
// One block per 32-row tile. afrag index: (((tile*16+s)*8 + sl*2+half)*32 + m)*8
__global__ __launch_bounds__(256) void feats_kernel(const float* __restrict__ xin,
                                                    unsigned short* __restrict__ afrag){
  __shared__ float xs[32][129];
  const int t = threadIdx.x;
  const int tile = blockIdx.x;
  const int row0 = tile*32;
#pragma unroll
  for (int q=0;q<4;++q){
    int p = q*256 + t;          // float4 index: row = p>>5, c4 = p&31
    int r = p >> 5, c4 = p & 31;
    int grow = row0 + r;
    float4 v = make_float4(0.f,0.f,0.f,0.f);
    if (grow < NN) v = *(const float4*)(xin + (size_t)grow*DD + c4*4);
    xs[r][c4*4+0]=v.x; xs[r][c4*4+1]=v.y; xs[r][c4*4+2]=v.z; xs[r][c4*4+3]=v.w;
  }
  __syncthreads();
  const int m = t & 31, half = (t>>5)&1, sl = t>>6;
  unsigned short* ab = afrag + (size_t)tile*32768;
#pragma unroll
  for (int s=0;s<16;++s){
    int i = s*8 + sl*2 + half;
    int4 pk = kan_feats_pack(xs[m][i]);
    *(int4*)(ab + (size_t)((s*8 + sl*2 + half)*32 + m)*8) = pk;
  }
}

// ---------------- KANLinear via bf16 MFMA, A & B both pre-swizzled ----------------
// Block 256 = 4 waves; tile 64 rows x 128 cols; wave tile 32x64 (2 MFMA tiles).
// B double-buffered in LDS; A read directly from global (coalesced int4), prefetched.
__global__ __launch_bounds__(256) void kan_gemm(const unsigned short* __restrict__ afrag,
                                                const unsigned short* __restrict__ wfrag,
                                                float* __restrict__ hlin, int layer)
{
  __shared__ __align__(16) unsigned short Bs[2][8192];
  const int t    = threadIdx.x;
  const int lane = t & 63;
  const int w    = t >> 6;
  const int wm   = w & 1;
  const int wn   = w >> 1;
  const int half = lane >> 5;
  const int mn   = lane & 31;
  const int row0 = blockIdx.x * 64;
  const unsigned short* wl = wfrag + layer*131072;
  const unsigned short* ab = afrag + (size_t)(blockIdx.x*2 + wm)*32768;

  float16_t acc0, acc1;
#pragma unroll
  for (int i=0;i<16;++i){ acc0[i]=0.f; acc1[i]=0.f; }

  // prologue: stage B for s=0, load A for s=0
#pragma unroll
  for (int q=0;q<4;++q){
    int eo = q*2048 + t*8;
    *(int4*)(&Bs[0][eo]) = *(const int4*)(wl + eo);
  }
  int4 Ac[4], An[4];
#pragma unroll
  for (int sl=0;sl<4;++sl)
    Ac[sl] = *(const int4*)(ab + (size_t)(((0*8) + sl*2 + half)*32 + mn)*8);

  for (int s=0; s<16; ++s){
    __syncthreads();
    if (s < 15){
      const unsigned short* wsrc = wl + (s+1)*8192;
#pragma unroll
      for (int q=0;q<4;++q){
        int eo = q*2048 + t*8;
        *(int4*)(&Bs[(s+1)&1][eo]) = *(const int4*)(wsrc + eo);
      }
#pragma unroll
      for (int sl=0;sl<4;++sl)
        An[sl] = *(const int4*)(ab + (size_t)((((s+1)*8) + sl*2 + half)*32 + mn)*8);
    }
    const unsigned short* B = Bs[s&1];
#pragma unroll
    for (int sl=0; sl<4; ++sl){
      bf16x8 a = __builtin_bit_cast(bf16x8, Ac[sl]);
      int4 b0i = *(const int4*)(B + (((wn*2+0)*4 + sl)*64 + lane)*8);
      int4 b1i = *(const int4*)(B + (((wn*2+1)*4 + sl)*64 + lane)*8);
      acc0 = __builtin_amdgcn_mfma_f32_32x32x16_bf16(a, __builtin_bit_cast(bf16x8, b0i), acc0, 0, 0, 0);
      acc1 = __builtin_amdgcn_mfma_f32_32x32x16_bf16(a, __builtin_bit_cast(bf16x8, b1i), acc1, 0, 0, 0);
    }
#pragma unroll
    for (int sl=0;sl<4;++sl) Ac[sl] = An[sl];
  }

  // epilogue: C/D layout col=lane&31, row=(reg&3)+8*(reg>>2)+4*(lane>>5)
#pragma unroll
  for (int nt=0; nt<2; ++nt){
    const float16_t* a = nt ? &acc1 : &acc0;
#pragma unroll
    for (int reg=0; reg<16; ++reg){
      int r = (reg&3) + 8*(reg>>2) + 4*half;
      int row = row0 + wm*32 + r;
      int col = wn*64 + nt*32 + mn;
      if (row < NN) hlin[row*DD + col] = (*a)[reg];
    }
  }
}

// ---------------- attention logits a_src/a_dst per (node, head) ----------------
__global__ __launch_bounds__(256) void attlog_kernel(const float* __restrict__ hlin,
    const float* __restrict__ attS, const float* __restrict__ attD,
    float* __restrict__ asrc, float* __restrict__ adst, int layer)
{
  int t = blockIdx.x*256 + threadIdx.x;
  if (t >= NN*4) return;
  int n = t >> 2, h = t & 3;
  const float4* hp = (const float4*)(hlin + n*DD + h*32);
  const float4* ws = (const float4*)(attS + (layer*4 + h)*32);
  const float4* wd = (const float4*)(attD + (layer*4 + h)*32);
  float ss = 0.f, sd = 0.f;
#pragma unroll
  for (int j=0;j<8;++j){
    float4 hv = hp[j]; float4 a = ws[j]; float4 b = wd[j];
    ss += hv.x*a.x + hv.y*a.y + hv.z*a.z + hv.w*a.w;
    sd += hv.x*b.x + hv.y*b.y + hv.z*b.z + hv.w*b.w;
  }
  asrc[t] = ss; adst[t] = sd;
}

// ---------------- GAT aggregation: (edge,head)-parallel softmax, shuffle-broadcast ----------------
__global__ __launch_bounds__(256) void attn_kernel(
    const float* __restrict__ hlin, const float* __restrict__ asrc, const float* __restrict__ adst,
    const int* __restrict__ offs, const int* __restrict__ deg, const int* __restrict__ csr,
    const float* __restrict__ bias, float* __restrict__ hout, int layer)
{
  const int wave = threadIdx.x >> 6;
  const int lane = threadIdx.x & 63;
  const int n = blockIdx.x*4 + wave;
  if (n >= NN) return;
  const int st = offs[n];
  const int d  = deg[n];
  const int eL = lane >> 2, h = lane & 3;
  const float adh = adst[n*4 + h];

  int sI = 0; float ev = -3.4e38f;
  const bool val0 = (eL < d);
  if (val0){
    sI = csr[st + eL];
    float av = asrc[sI*4 + h];
    float e0 = av + adh;
    ev = (e0 > 0.f) ? e0 : 0.2f*e0;
  }
  float mL = ev;
  for (int c=16; c<d; c+=16){
    int e = c + eL;
    if (e < d){
      int s2 = csr[st + e];
      float av = asrc[s2*4 + h];
      float e0 = av + adh;
      float evv = (e0 > 0.f) ? e0 : 0.2f*e0;
      mL = fmaxf(mL, evv);
    }
  }
#pragma unroll
  for (int o=4;o<64;o<<=1) mL = fmaxf(mL, __shfl_xor(mL, o));
  float a0 = val0 ? __expf(ev - mL) : 0.f;
  float sL = a0;
  for (int c=16; c<d; c+=16){
    int e = c + eL;
    if (e < d){
      int s2 = csr[st + e];
      float av = asrc[s2*4 + h];
      float e0 = av + adh;
      float evv = (e0 > 0.f) ? e0 : 0.2f*e0;
      sL += __expf(evv - mL);
    }
  }
#pragma unroll
  for (int o=4;o<64;o<<=1) sL += __shfl_xor(sL, o);
  const float inv = 1.f/(sL + 1e-16f);

  const int hc0 = lane >> 5;
  float acc0 = 0.f, acc1 = 0.f;
  {
    float al = a0 * inv;
    int lim = (d < 16) ? d : 16;
    for (int j=0;j<lim;++j){
      int srcj = __shfl(sI, j*4);
      float aA = __shfl(al, j*4 + hc0);
      float aB = __shfl(al, j*4 + 2 + hc0);
      const float* hr = hlin + (size_t)srcj*DD;
      acc0 = fmaf(aA, hr[lane],      acc0);
      acc1 = fmaf(aB, hr[lane + 64], acc1);
    }
  }
  for (int c=16; c<d; c+=16){
    int e = c + eL;
    int s2 = 0; float al = 0.f;
    if (e < d){
      s2 = csr[st + e];
      float av = asrc[s2*4 + h];
      float e0 = av + adh;
      float evv = (e0 > 0.f) ? e0 : 0.2f*e0;
      al = __expf(evv - mL) * inv;
    }
    int lim = ((d - c) < 16) ? (d - c) : 16;
    for (int j=0;j<lim;++j){
      int srcj = __shfl(s2, j*4);
      float aA = __shfl(al, j*4 + hc0);
      float aB = __shfl(al, j*4 + 2 + hc0);
      const float* hr = hlin + (size_t)srcj*DD;
      acc0 = fmaf(aA, hr[lane],      acc0);
      acc1 = fmaf(aB, hr[lane + 64], acc1);
    }
  }
  float o0 = siluf(acc0 + bias[layer*DD + lane]);
  float o1 = siluf(acc1 + bias[layer*DD + lane + 64]);
  hout[n*DD + lane]      = o0;
  hout[n*DD + lane + 64] = o1;
}

// ---------------- global_add_pool (batch is sorted) ----------------
__global__ __launch_bounds__(128) void pool_kernel(const float* __restrict__ h,
    const int* __restrict__ batch, float* __restrict__ pooled)
{
  int c = threadIdx.x;
  int n0 = blockIdx.x*128;
  float sum = 0.f; int cur = -1;
  for (int r=0;r<128;++r){
    int n = n0 + r;
    if (n >= NN) break;
    int g = batch[n];
    if (g != cur){
      if (cur >= 0) atomicAdd(&pooled[cur*DD + c], sum);
      cur = g; sum = 0.f;
    }
    sum += h[n*DD + c];
  }
  if (cur >= 0) atomicAdd(&pooled[cur*DD + c], sum);
}

// ---------------- KAN readout + log_softmax (1 block per graph) ----------------
__global__ __launch_bounds__(64) void readout_kernel(const float* __restrict__ pooled,
    const float* __restrict__ bw, const float* __restrict__ sw, const float* __restrict__ sc,
    float* __restrict__ out)
{
  int g = blockIdx.x, lane = threadIdx.x;
  float xa = pooled[g*DD + lane];
  float xb = pooled[g*DD + lane + 64];
  float fa[8], fb[8];
  kan_feats(xa, fa);
  kan_feats(xb, fb);
  float logits[NCL];
#pragma unroll
  for (int c=0;c<NCL;++c){
    int ia = c*DD + lane, ib = ia + 64;
    float sca = sc[ia], scb = sc[ib];
    float p = fa[0]*bw[ia] + fb[0]*bw[ib];
#pragma unroll
    for (int f=1;f<8;++f)
      p += fa[f]*sw[ia*7 + f-1]*sca + fb[f]*sw[ib*7 + f-1]*scb;
#pragma unroll
    for (int o=1;o<64;o<<=1) p += __shfl_xor(p, o);
    logits[c] = p;
  }
  float mx = logits[0];
#pragma unroll
  for (int c=1;c<NCL;++c) mx = fmaxf(mx, logits[c]);
  float lse = 0.f;
#pragma unroll
  for (int c=0;c<NCL;++c) lse += __expf(logits[c]-mx);
  lse = mx + logf(lse);
  if (lane < NCL){
    float v = 0.f;
#pragma unroll
    for (int c=0;c<NCL;++c) if (lane == c) v = logits[c] - lse;
    out[g*NCL + lane] = v;
  }
}

// ---------------- host ----------------
extern "C" void kernel_launch(void* const* d_in, const int* in_sizes, int n_in,
                              void* d_out, int out_size, void* d_ws, size_t ws_size,
                              hipStream_t stream)
{
  const float* x        = (const float*)d_in[0];
  const int*   ei       = (const int*)  d_in[1];
  const int*   batch    = (const int*)  d_in[2];
  const float* base_w   = (const float*)d_in[3];
  const float* spline_w = (const float*)d_in[4];
  const float* scaler   = (const float*)d_in[5];
  const float* att_src  = (const float*)d_in[6];
  const float* att_dst  = (const float*)d_in[7];
  const float* bias     = (const float*)d_in[8];
  const float* ro_bw    = (const float*)d_in[9];
  const float* ro_sw    = (const float*)d_in[10];
  const float* ro_sc    = (const float*)d_in[11];
  float* out = (float*)d_out;

  char* p = (char*)d_ws;
  auto alloc = [&](size_t bytes)->char* {
    char* r = p;
    p += (bytes + 255) & ~(size_t)255;
    return r;
  };
  const int NTILE = 1564;                      // ceil(50000/32) rounded to even (782 blocks x 2)
  float* hlin   = (float*)alloc((size_t)NN*DD*4);
  float* hbuf   = (float*)alloc((size_t)NN*DD*4);
  unsigned short* wfrag = (unsigned short*)alloc((size_t)3*131072*2);
  unsigned short* afrag = (unsigned short*)alloc((size_t)NTILE*32768*2);
  float* asrc   = (float*)alloc((size_t)NN*4*4);
  float* adst   = (float*)alloc((size_t)NN*4*4);
  float* pooled = (float*)alloc((size_t)NGR*DD*4);
  int*   deg    = (int*)alloc((size_t)NN*4);
  int*   offs   = (int*)alloc((size_t)NN*4);
  int*   cursor = (int*)alloc((size_t)NN*4);
  int*   csr    = (int*)alloc((size_t)ETOT*4);
  int*   part   = (int*)alloc((size_t)256*4);

  const int nbs = (NN + 255)/256;
  hipMemsetAsync(deg, 0, (size_t)NN*sizeof(int), stream);
  hist_kernel <<<(ETOT+255)/256, 256, 0, stream>>>(ei, deg);
  scan1_kernel<<<nbs, 256, 0, stream>>>(deg, offs, part);
  scan2_kernel<<<1,   256, 0, stream>>>(part, nbs);
  scan3_kernel<<<nbs, 256, 0, stream>>>(offs, part, cursor);
  fill_kernel <<<(ETOT+255)/256, 256, 0, stream>>>(ei, cursor, csr);
  build_wfrag <<<(3*128*1024)/256, 256, 0, stream>>>(base_w, spline_w, scaler, wfrag);

  const float* cur = x;
  for (int l=0; l<3; ++l){
    feats_kernel <<<NTILE,         256, 0, stream>>>(cur, afrag);
    kan_gemm     <<<(NN+63)/64,    256, 0, stream>>>(afrag, wfrag, hlin, l);
    attlog_kernel<<<(NN*4+255)/256,256, 0, stream>>>(hlin, att_src, att_dst, asrc, adst, l);
    attn_kernel  <<<(NN+3)/4,      256, 0, stream>>>(hlin, asrc, adst, offs, deg, csr, bias, hbuf, l);
    cur = hbuf;
  }
  hipMemsetAsync(pooled, 0, (size_t)NGR*DD*sizeof(float), stream);
  pool_kernel   <<<(NN+127)/128, 128, 0, stream>>>(hbuf, batch, pooled);
  readout_kernel<<<NGR, 64, 0, stream>>>(pooled, ro_bw, ro_sw, ro_sc, out);
}

// Round 5
// 583.508 us; speedup vs baseline: 2.1866x; 1.1181x over previous
//
#include <hip/hip_runtime.h>
#include <math.h>

#define NN 50000
#define EE 800000
#define ETOT (EE + NN)
#define NGR 64
#define DD 128
#define NCL 10

typedef __attribute__((ext_vector_type(16))) float float16_t;
typedef __attribute__((ext_vector_type(8)))  __bf16 bf16x8;

// ---------------- device helpers ----------------
__device__ __forceinline__ float siluf(float x){ return x / (1.f + __expf(-x)); }

__device__ __forceinline__ unsigned f2bf(float f){
  union { float f; unsigned u; } v; v.f = f;
  unsigned r = v.u + 0x7fffu + ((v.u >> 16) & 1u);
  return (r >> 16) & 0xffffu;
}

// 8 KAN features of scalar x: [silu(x), B0..B6] (float version for readout)
__device__ __forceinline__ void kan_feats(float x, float* f8){
  f8[0] = siluf(x);
  float u = 2.f*x + 5.f;
  int cell = -1;
  float n0=0.f,n1=0.f,n2=0.f,n3=0.f;
  if (u >= 0.f && u < 10.f){
    cell = (int)u;
    float t = u - (float)cell;
    float t2 = t*t, t3 = t2*t;
    float omt = 1.f - t;
    const float s6 = 1.f/6.f;
    n0 = t3*s6;
    n1 = s6*(1.f + 3.f*t + 3.f*t2 - 3.f*t3);
    n2 = s6*(4.f - 6.f*t2 + 3.f*t3);
    n3 = omt*omt*omt*s6;
  }
#pragma unroll
  for (int j=0;j<7;++j){
    int k = cell - j;
    float v = (k==0)?n0:((k==1)?n1:((k==2)?n2:((k==3)?n3:0.f)));
    f8[1+j] = v;
  }
}

// Packed bf16 A-fragment of scalar x: us[0..7] = [silu, B0..B6] via 64-bit shift.
__device__ __forceinline__ int4 kan_feats_pack(float x){
  unsigned sbf = f2bf(siluf(x));
  float u = 2.f*x + 5.f;
  bool valid = (u >= 0.f) && (u < 10.f);
  float uc = valid ? u : 0.f;
  int cell = (int)uc;
  float t = uc - (float)cell;
  float t2 = t*t, t3 = t2*t, omt = 1.f - t;
  const float s6 = 1.f/6.f;
  float n0 = t3*s6;
  float n1 = s6*(1.f + 3.f*t + 3.f*t2 - 3.f*t3);
  float n2 = s6*(4.f - 6.f*t2 + 3.f*t3);
  float n3 = omt*omt*omt*s6;
  unsigned p0=f2bf(n0), p1=f2bf(n1), p2=f2bf(n2), p3=f2bf(n3);
  unsigned long long P = ((unsigned long long)(p1 | (p0<<16)) << 32)
                       |  (unsigned long long)(p3 | (p2<<16));
  int sh = cell*16 - 48;
  unsigned long long shl    = P << (sh & 63);
  unsigned long long shrhi  = P >> ((64 - sh) & 63);
  unsigned long long shllo2 = P << ((sh - 64) & 63);
  unsigned long long shrlo  = P >> ((-sh) & 63);
  unsigned long long F0, F1;
  if (sh < 0)       { F0 = shrlo; F1 = 0ull; }
  else if (sh < 64) { F0 = shl;   F1 = (sh==0)? 0ull : shrhi; }
  else              { F0 = 0ull;  F1 = shllo2; }
  if (!valid){ F0 = 0ull; F1 = 0ull; }
  unsigned w0 = ((unsigned)(F0 & 0xffffull) << 16) | sbf;
  unsigned w1 = (unsigned)((F0 >> 16) & 0xffffffffull);
  unsigned w2 = (unsigned)((F0 >> 48) & 0xffffull) | (((unsigned)(F1 & 0xffffull)) << 16);
  unsigned w3 = (unsigned)((F1 >> 16) & 0xffffffffull);
  return make_int4((int)w0,(int)w1,(int)w2,(int)w3);
}

// ---------------- CSR build (dst-indexed) ----------------
__global__ void hist_kernel(const int* __restrict__ ei, int* __restrict__ deg){
  int e = blockIdx.x*256 + threadIdx.x;
  if (e >= ETOT) return;
  int dst = (e < EE) ? ei[EE + e] : (e - EE);
  atomicAdd(&deg[dst], 1);
}

__global__ void scan1_kernel(const int* __restrict__ deg, int* __restrict__ offs, int* __restrict__ part){
  __shared__ int sh[256];
  int tid = threadIdx.x;
  int i = blockIdx.x*256 + tid;
  int v = (i < NN) ? deg[i] : 0;
  sh[tid] = v; __syncthreads();
  for (int o=1;o<256;o<<=1){
    int t2 = (tid >= o) ? sh[tid - o] : 0;
    __syncthreads();
    sh[tid] += t2;
    __syncthreads();
  }
  int incl = sh[tid];
  if (i < NN) offs[i] = incl - v;
  if (tid == 255) part[blockIdx.x] = incl;
}

__global__ void scan2_kernel(int* __restrict__ part, int nb){
  __shared__ int sh[256];
  int tid = threadIdx.x;
  int v = (tid < nb) ? part[tid] : 0;
  sh[tid] = v; __syncthreads();
  for (int o=1;o<256;o<<=1){
    int t2 = (tid >= o) ? sh[tid - o] : 0;
    __syncthreads();
    sh[tid] += t2;
    __syncthreads();
  }
  if (tid < nb) part[tid] = sh[tid] - v;
}

__global__ void scan3_kernel(int* __restrict__ offs, const int* __restrict__ part, int* __restrict__ cursor){
  int i = blockIdx.x*256 + threadIdx.x;
  if (i >= NN) return;
  int o = offs[i] + part[blockIdx.x];
  offs[i] = o;
  cursor[i] = o;
}

__global__ void fill_kernel(const int* __restrict__ ei, int* __restrict__ cursor, int* __restrict__ csr){
  int e = blockIdx.x*256 + threadIdx.x;
  if (e >= ETOT) return;
  int src, dst;
  if (e < EE){ src = ei[e]; dst = ei[EE + e]; } else { src = e - EE; dst = e - EE; }
  int pos = atomicAdd(&cursor[dst], 1);
  csr[pos] = src;
}

// ---------------- fold weights into bf16, MFMA-fragment order ----------------
__global__ void build_wfrag(const float* __restrict__ bw, const float* __restrict__ sw,
                            const float* __restrict__ sc, unsigned short* __restrict__ wfrag){
  int idx = blockIdx.x*256 + threadIdx.x;
  if (idx >= 3*128*1024) return;
  int k = idx & 1023;
  int o = (idx >> 10) & 127;
  int l = idx >> 17;
  int i = k >> 3, f = k & 7;
  int oi = (l*DD + o)*DD + i;
  float w = (f == 0) ? bw[oi] : sw[oi*7 + (f-1)] * sc[oi];
  int s = k >> 6;
  int sl = (k >> 4) & 3, half = (k >> 3) & 1, j = k & 7;
  int ntile = o >> 5, n = o & 31;
  int dst = l*131072 + s*8192 + (((ntile*4 + sl)*64) + half*32 + n)*8 + j;
  wfrag[dst] = (unsigned short)f2bf(w);
}

// ---------------- fused KAN feats + GEMM + bf16 pack epilogue ----------------
// 782 blocks x 256 thr (4 waves). Tile 64 rows x 128 cols; wave w = cols w*32..+31.
// Per stage (K=64): each thread computes 2 kan_feats_packs (next stage, pipelined)
// into 8 KB LDS A-frag buffer; B prefetched from L2 into registers. Output: hpack
// uint = (bf16 h[2j]) | (bf16 h[2j+1] << 16).
__global__ __launch_bounds__(256) void kan_gemm(const float* __restrict__ xin,
                                                const unsigned short* __restrict__ wfrag,
                                                unsigned int* __restrict__ hpack, int layer)
{
  __shared__ __align__(16) float xs[64*132];          // 33 KB; reused as hs[64][136] ushort in epilogue
  __shared__ __align__(16) unsigned short Afrag[4096]; // 8 KB: ((mt*8+il)*32+m)*8
  const int t    = threadIdx.x;
  const int lane = t & 63;
  const int w    = t >> 6;
  const int half = lane >> 5;
  const int mn   = lane & 31;
  const int row0 = blockIdx.x * 64;
  const int r_my = t & 63;
  const int il0  = t >> 6;           // this thread's il pair: il0, il0+4
  const unsigned short* wl = wfrag + layer*131072;

  // stage x tile (64 x 128 f32), coalesced float4
#pragma unroll
  for (int q=0;q<8;++q){
    int p = q*256 + t;
    int r = p >> 5, c4 = p & 31;
    int grow = row0 + r;
    float4 v = make_float4(0.f,0.f,0.f,0.f);
    if (grow < NN) v = *(const float4*)(xin + (size_t)grow*DD + c4*4);
    *(float4*)(&xs[r*132 + c4*4]) = v;
  }
  __syncthreads();

  float16_t acc[2];
#pragma unroll
  for (int i=0;i<16;++i){ acc[0][i]=0.f; acc[1][i]=0.f; }

  int4 Bc[4], Bn[4];
#pragma unroll
  for (int sl=0;sl<4;++sl)
    Bc[sl] = *(const int4*)(wl + ((w*4+sl)*64 + lane)*8);

  // packs for s=0
  int4 Pa = kan_feats_pack(xs[r_my*132 + il0]);
  int4 Pb = kan_feats_pack(xs[r_my*132 + il0 + 4]);
  {
    int foa = (((r_my>>5)*8 + il0)*32 + (r_my&31))*8;
    int fob = (((r_my>>5)*8 + il0+4)*32 + (r_my&31))*8;
    *(int4*)(Afrag + foa) = Pa;
    *(int4*)(Afrag + fob) = Pb;
  }

  for (int s=0; s<16; ++s){
    __syncthreads();                       // Afrag(s) visible
    if (s < 15){
      const unsigned short* wsrc = wl + (s+1)*8192;
#pragma unroll
      for (int sl=0;sl<4;++sl)
        Bn[sl] = *(const int4*)(wsrc + ((w*4+sl)*64 + lane)*8);
      Pa = kan_feats_pack(xs[r_my*132 + (s+1)*8 + il0]);
      Pb = kan_feats_pack(xs[r_my*132 + (s+1)*8 + il0 + 4]);
    }
#pragma unroll
    for (int sl=0; sl<4; ++sl){
      int4 a0i = *(const int4*)(Afrag + (((0*8 + sl*2 + half)*32) + mn)*8);
      int4 a1i = *(const int4*)(Afrag + (((1*8 + sl*2 + half)*32) + mn)*8);
      bf16x8 b = __builtin_bit_cast(bf16x8, Bc[sl]);
      acc[0] = __builtin_amdgcn_mfma_f32_32x32x16_bf16(__builtin_bit_cast(bf16x8, a0i), b, acc[0], 0, 0, 0);
      acc[1] = __builtin_amdgcn_mfma_f32_32x32x16_bf16(__builtin_bit_cast(bf16x8, a1i), b, acc[1], 0, 0, 0);
    }
    __syncthreads();                       // all waves done reading Afrag(s)
    if (s < 15){
      int foa = (((r_my>>5)*8 + il0)*32 + (r_my&31))*8;
      int fob = (((r_my>>5)*8 + il0+4)*32 + (r_my&31))*8;
      *(int4*)(Afrag + foa) = Pa;
      *(int4*)(Afrag + fob) = Pb;
#pragma unroll
      for (int sl=0;sl<4;++sl) Bc[sl] = Bn[sl];
    }
  }

  // epilogue: acc -> bf16 -> LDS -> packed uint store
  unsigned short* hs = (unsigned short*)xs;   // hs[64][136]
  __syncthreads();
#pragma unroll
  for (int mt=0; mt<2; ++mt){
#pragma unroll
    for (int reg=0; reg<16; ++reg){
      int row = mt*32 + (reg&3) + 8*(reg>>2) + 4*half;
      int col = w*32 + mn;
      hs[row*136 + col] = (unsigned short)f2bf(acc[mt][reg]);
    }
  }
  __syncthreads();
#pragma unroll
  for (int q=0;q<4;++q){
    int p = q*256 + t;                 // uint4 index: row = p>>4, u4 = p&15
    int row = p >> 4, u4 = p & 15;
    uint4 v = *(const uint4*)((const unsigned int*)(hs + row*136) + u4*4);
    int grow = row0 + row;
    if (grow < NN) *(uint4*)(hpack + (size_t)grow*64 + u4*4) = v;
  }
}

// ---------------- attention logits from packed h ----------------
__global__ __launch_bounds__(256) void attlog_kernel(const unsigned int* __restrict__ hpack,
    const float* __restrict__ attS, const float* __restrict__ attD,
    float* __restrict__ asrc, float* __restrict__ adst, int layer)
{
  int t = blockIdx.x*256 + threadIdx.x;
  if (t >= NN*4) return;
  int n = t >> 2, h = t & 3;
  const uint4* hp = (const uint4*)(hpack + (size_t)n*64 + h*16);
  const float* ws = attS + (layer*4 + h)*32;
  const float* wd = attD + (layer*4 + h)*32;
  float ss = 0.f, sd = 0.f;
#pragma unroll
  for (int q=0;q<4;++q){
    uint4 v = hp[q];
    unsigned uu[4] = {v.x, v.y, v.z, v.w};
#pragma unroll
    for (int e=0;e<4;++e){
      float flo = __uint_as_float(uu[e] << 16);
      float fhi = __uint_as_float(uu[e] & 0xffff0000u);
      int c = q*8 + e*2;
      ss += flo*ws[c] + fhi*ws[c+1];
      sd += flo*wd[c] + fhi*wd[c+1];
    }
  }
  asrc[t] = ss; adst[t] = sd;
}

// ---------------- GAT aggregation: packed-bf16 gather ----------------
// One wave per dst node. Softmax lanes: eL = lane>>2, h = lane&3.
// Channel pass: lane covers channels (2*lane, 2*lane+1), head hq = lane>>4.
__global__ __launch_bounds__(256) void attn_kernel(
    const unsigned int* __restrict__ hpack, const float* __restrict__ asrc, const float* __restrict__ adst,
    const int* __restrict__ offs, const int* __restrict__ deg, const int* __restrict__ csr,
    const float* __restrict__ bias, float* __restrict__ hout, int layer)
{
  const int wave = threadIdx.x >> 6;
  const int lane = threadIdx.x & 63;
  const int n = blockIdx.x*4 + wave;
  if (n >= NN) return;
  const int st = offs[n];
  const int d  = deg[n];
  const int eL = lane >> 2, h = lane & 3;
  const float adh = adst[n*4 + h];

  int sI = 0; float ev = -3.4e38f;
  const bool val0 = (eL < d);
  if (val0){
    sI = csr[st + eL];
    float av = asrc[sI*4 + h];
    float e0 = av + adh;
    ev = (e0 > 0.f) ? e0 : 0.2f*e0;
  }
  float mL = ev;
  for (int c=16; c<d; c+=16){
    int e = c + eL;
    if (e < d){
      int s2 = csr[st + e];
      float av = asrc[s2*4 + h];
      float e0 = av + adh;
      float evv = (e0 > 0.f) ? e0 : 0.2f*e0;
      mL = fmaxf(mL, evv);
    }
  }
#pragma unroll
  for (int o=4;o<64;o<<=1) mL = fmaxf(mL, __shfl_xor(mL, o));
  float a0 = val0 ? __expf(ev - mL) : 0.f;
  float sL = a0;
  for (int c=16; c<d; c+=16){
    int e = c + eL;
    if (e < d){
      int s2 = csr[st + e];
      float av = asrc[s2*4 + h];
      float e0 = av + adh;
      float evv = (e0 > 0.f) ? e0 : 0.2f*e0;
      sL += __expf(evv - mL);
    }
  }
#pragma unroll
  for (int o=4;o<64;o<<=1) sL += __shfl_xor(sL, o);
  const float inv = 1.f/(sL + 1e-16f);

  const int hq = lane >> 4;          // head of channel 2*lane
  float accL = 0.f, accH = 0.f;
  {
    float al = a0 * inv;
    int lim = (d < 16) ? d : 16;
    for (int j=0;j<lim;++j){
      int srcj = __shfl(sI, j*4);
      float aH = __shfl(al, j*4 + hq);
      unsigned u = hpack[(size_t)srcj*64 + lane];
      accL = fmaf(aH, __uint_as_float(u << 16),         accL);
      accH = fmaf(aH, __uint_as_float(u & 0xffff0000u), accH);
    }
  }
  for (int c=16; c<d; c+=16){
    int e = c + eL;
    int s2 = 0; float al = 0.f;
    if (e < d){
      s2 = csr[st + e];
      float av = asrc[s2*4 + h];
      float e0 = av + adh;
      float evv = (e0 > 0.f) ? e0 : 0.2f*e0;
      al = __expf(evv - mL) * inv;
    }
    int lim = ((d - c) < 16) ? (d - c) : 16;
    for (int j=0;j<lim;++j){
      int srcj = __shfl(s2, j*4);
      float aH = __shfl(al, j*4 + hq);
      unsigned u = hpack[(size_t)srcj*64 + lane];
      accL = fmaf(aH, __uint_as_float(u << 16),         accL);
      accH = fmaf(aH, __uint_as_float(u & 0xffff0000u), accH);
    }
  }
  float2 bv = *(const float2*)(bias + layer*DD + 2*lane);
  float o0 = siluf(accL + bv.x);
  float o1 = siluf(accH + bv.y);
  *(float2*)(hout + (size_t)n*DD + 2*lane) = make_float2(o0, o1);
}

// ---------------- global_add_pool (batch is sorted) ----------------
__global__ __launch_bounds__(128) void pool_kernel(const float* __restrict__ h,
    const int* __restrict__ batch, float* __restrict__ pooled)
{
  int c = threadIdx.x;
  int n0 = blockIdx.x*128;
  float sum = 0.f; int cur = -1;
  for (int r=0;r<128;++r){
    int n = n0 + r;
    if (n >= NN) break;
    int g = batch[n];
    if (g != cur){
      if (cur >= 0) atomicAdd(&pooled[cur*DD + c], sum);
      cur = g; sum = 0.f;
    }
    sum += h[n*DD + c];
  }
  if (cur >= 0) atomicAdd(&pooled[cur*DD + c], sum);
}

// ---------------- KAN readout + log_softmax (1 block per graph) ----------------
__global__ __launch_bounds__(64) void readout_kernel(const float* __restrict__ pooled,
    const float* __restrict__ bw, const float* __restrict__ sw, const float* __restrict__ sc,
    float* __restrict__ out)
{
  int g = blockIdx.x, lane = threadIdx.x;
  float xa = pooled[g*DD + lane];
  float xb = pooled[g*DD + lane + 64];
  float fa[8], fb[8];
  kan_feats(xa, fa);
  kan_feats(xb, fb);
  float logits[NCL];
#pragma unroll
  for (int c=0;c<NCL;++c){
    int ia = c*DD + lane, ib = ia + 64;
    float sca = sc[ia], scb = sc[ib];
    float p = fa[0]*bw[ia] + fb[0]*bw[ib];
#pragma unroll
    for (int f=1;f<8;++f)
      p += fa[f]*sw[ia*7 + f-1]*sca + fb[f]*sw[ib*7 + f-1]*scb;
#pragma unroll
    for (int o=1;o<64;o<<=1) p += __shfl_xor(p, o);
    logits[c] = p;
  }
  float mx = logits[0];
#pragma unroll
  for (int c=1;c<NCL;++c) mx = fmaxf(mx, logits[c]);
  float lse = 0.f;
#pragma unroll
  for (int c=0;c<NCL;++c) lse += __expf(logits[c]-mx);
  lse = mx + logf(lse);
  if (lane < NCL){
    float v = 0.f;
#pragma unroll
    for (int c=0;c<NCL;++c) if (lane == c) v = logits[c] - lse;
    out[g*NCL + lane] = v;
  }
}

// ---------------- host ----------------
extern "C" void kernel_launch(void* const* d_in, const int* in_sizes, int n_in,
                              void* d_out, int out_size, void* d_ws, size_t ws_size,
                              hipStream_t stream)
{
  const float* x        = (const float*)d_in[0];
  const int*   ei       = (const int*)  d_in[1];
  const int*   batch    = (const int*)  d_in[2];
  const float* base_w   = (const float*)d_in[3];
  const float* spline_w = (const float*)d_in[4];
  const float* scaler   = (const float*)d_in[5];
  const float* att_src  = (const float*)d_in[6];
  const float* att_dst  = (const float*)d_in[7];
  const float* bias     = (const float*)d_in[8];
  const float* ro_bw    = (const float*)d_in[9];
  const float* ro_sw    = (const float*)d_in[10];
  const float* ro_sc    = (const float*)d_in[11];
  float* out = (float*)d_out;

  char* p = (char*)d_ws;
  auto alloc = [&](size_t bytes)->char* {
    char* r = p;
    p += (bytes + 255) & ~(size_t)255;
    return r;
  };
  unsigned int* hpack = (unsigned int*)alloc((size_t)50048*64*4);
  float* hbuf   = (float*)alloc((size_t)NN*DD*4);
  unsigned short* wfrag = (unsigned short*)alloc((size_t)3*131072*2);
  float* asrc   = (float*)alloc((size_t)NN*4*4);
  float* adst   = (float*)alloc((size_t)NN*4*4);
  float* pooled = (float*)alloc((size_t)NGR*DD*4);
  int*   deg    = (int*)alloc((size_t)NN*4);
  int*   offs   = (int*)alloc((size_t)NN*4);
  int*   cursor = (int*)alloc((size_t)NN*4);
  int*   csr    = (int*)alloc((size_t)ETOT*4);
  int*   part   = (int*)alloc((size_t)256*4);

  const int nbs = (NN + 255)/256;
  hipMemsetAsync(deg, 0, (size_t)NN*sizeof(int), stream);
  hist_kernel <<<(ETOT+255)/256, 256, 0, stream>>>(ei, deg);
  scan1_kernel<<<nbs, 256, 0, stream>>>(deg, offs, part);
  scan2_kernel<<<1,   256, 0, stream>>>(part, nbs);
  scan3_kernel<<<nbs, 256, 0, stream>>>(offs, part, cursor);
  fill_kernel <<<(ETOT+255)/256, 256, 0, stream>>>(ei, cursor, csr);
  build_wfrag <<<(3*128*1024)/256, 256, 0, stream>>>(base_w, spline_w, scaler, wfrag);

  const float* cur = x;
  for (int l=0; l<3; ++l){
    kan_gemm     <<<(NN+63)/64,    256, 0, stream>>>(cur, wfrag, hpack, l);
    attlog_kernel<<<(NN*4+255)/256,256, 0, stream>>>(hpack, att_src, att_dst, asrc, adst, l);
    attn_kernel  <<<(NN+3)/4,      256, 0, stream>>>(hpack, asrc, adst, offs, deg, csr, bias, hbuf, l);
    cur = hbuf;
  }
  hipMemsetAsync(pooled, 0, (size_t)NGR*DD*sizeof(float), stream);
  pool_kernel   <<<(NN+127)/128, 128, 0, stream>>>(hbuf, batch, pooled);
  readout_kernel<<<NGR, 64, 0, stream>>>(pooled, ro_bw, ro_sw, ro_sc, out);
}

// Round 6
// 493.931 us; speedup vs baseline: 2.5831x; 1.1814x over previous
//
#include <hip/hip_runtime.h>
#include <math.h>

#define NN 50000
#define EE 800000
#define ETOT (EE + NN)
#define NGR 64
#define DD 128
#define NCL 10

typedef __attribute__((ext_vector_type(16))) float float16_t;
typedef __attribute__((ext_vector_type(8)))  __bf16 bf16x8;

// ---------------- device helpers ----------------
__device__ __forceinline__ float siluf(float x){ return x / (1.f + __expf(-x)); }

__device__ __forceinline__ unsigned f2bf(float f){
  union { float f; unsigned u; } v; v.f = f;
  unsigned r = v.u + 0x7fffu + ((v.u >> 16) & 1u);
  return (r >> 16) & 0xffffu;
}

// 8 KAN features of scalar x: [silu(x), B0..B6] (float version for readout)
__device__ __forceinline__ void kan_feats(float x, float* f8){
  f8[0] = siluf(x);
  float u = 2.f*x + 5.f;
  int cell = -1;
  float n0=0.f,n1=0.f,n2=0.f,n3=0.f;
  if (u >= 0.f && u < 10.f){
    cell = (int)u;
    float t = u - (float)cell;
    float t2 = t*t, t3 = t2*t;
    float omt = 1.f - t;
    const float s6 = 1.f/6.f;
    n0 = t3*s6;
    n1 = s6*(1.f + 3.f*t + 3.f*t2 - 3.f*t3);
    n2 = s6*(4.f - 6.f*t2 + 3.f*t3);
    n3 = omt*omt*omt*s6;
  }
#pragma unroll
  for (int j=0;j<7;++j){
    int k = cell - j;
    float v = (k==0)?n0:((k==1)?n1:((k==2)?n2:((k==3)?n3:0.f)));
    f8[1+j] = v;
  }
}

// Packed bf16 A-fragment of scalar x: us[0..7] = [silu, B0..B6] via 64-bit shift.
__device__ __forceinline__ int4 kan_feats_pack(float x){
  unsigned sbf = f2bf(siluf(x));
  float u = 2.f*x + 5.f;
  bool valid = (u >= 0.f) && (u < 10.f);
  float uc = valid ? u : 0.f;
  int cell = (int)uc;
  float t = uc - (float)cell;
  float t2 = t*t, t3 = t2*t, omt = 1.f - t;
  const float s6 = 1.f/6.f;
  float n0 = t3*s6;
  float n1 = s6*(1.f + 3.f*t + 3.f*t2 - 3.f*t3);
  float n2 = s6*(4.f - 6.f*t2 + 3.f*t3);
  float n3 = omt*omt*omt*s6;
  unsigned p0=f2bf(n0), p1=f2bf(n1), p2=f2bf(n2), p3=f2bf(n3);
  unsigned long long P = ((unsigned long long)(p1 | (p0<<16)) << 32)
                       |  (unsigned long long)(p3 | (p2<<16));
  int sh = cell*16 - 48;
  unsigned long long shl    = P << (sh & 63);
  unsigned long long shrhi  = P >> ((64 - sh) & 63);
  unsigned long long shllo2 = P << ((sh - 64) & 63);
  unsigned long long shrlo  = P >> ((-sh) & 63);
  unsigned long long F0, F1;
  if (sh < 0)       { F0 = shrlo; F1 = 0ull; }
  else if (sh < 64) { F0 = shl;   F1 = (sh==0)? 0ull : shrhi; }
  else              { F0 = 0ull;  F1 = shllo2; }
  if (!valid){ F0 = 0ull; F1 = 0ull; }
  unsigned w0 = ((unsigned)(F0 & 0xffffull) << 16) | sbf;
  unsigned w1 = (unsigned)((F0 >> 16) & 0xffffffffull);
  unsigned w2 = (unsigned)((F0 >> 48) & 0xffffull) | (((unsigned)(F1 & 0xffffull)) << 16);
  unsigned w3 = (unsigned)((F1 >> 16) & 0xffffffffull);
  return make_int4((int)w0,(int)w1,(int)w2,(int)w3);
}

// ---------------- CSR build (dst-indexed) ----------------
__global__ void hist_kernel(const int* __restrict__ ei, int* __restrict__ deg){
  int e = blockIdx.x*256 + threadIdx.x;
  if (e >= ETOT) return;
  int dst = (e < EE) ? ei[EE + e] : (e - EE);
  atomicAdd(&deg[dst], 1);
}

__global__ void scan1_kernel(const int* __restrict__ deg, int* __restrict__ offs, int* __restrict__ part){
  __shared__ int sh[256];
  int tid = threadIdx.x;
  int i = blockIdx.x*256 + tid;
  int v = (i < NN) ? deg[i] : 0;
  sh[tid] = v; __syncthreads();
  for (int o=1;o<256;o<<=1){
    int t2 = (tid >= o) ? sh[tid - o] : 0;
    __syncthreads();
    sh[tid] += t2;
    __syncthreads();
  }
  int incl = sh[tid];
  if (i < NN) offs[i] = incl - v;
  if (tid == 255) part[blockIdx.x] = incl;
}

__global__ void scan2_kernel(int* __restrict__ part, int nb){
  __shared__ int sh[256];
  int tid = threadIdx.x;
  int v = (tid < nb) ? part[tid] : 0;
  sh[tid] = v; __syncthreads();
  for (int o=1;o<256;o<<=1){
    int t2 = (tid >= o) ? sh[tid - o] : 0;
    __syncthreads();
    sh[tid] += t2;
    __syncthreads();
  }
  if (tid < nb) part[tid] = sh[tid] - v;
}

__global__ void scan3_kernel(int* __restrict__ offs, const int* __restrict__ part, int* __restrict__ cursor){
  int i = blockIdx.x*256 + threadIdx.x;
  if (i >= NN) return;
  int o = offs[i] + part[blockIdx.x];
  offs[i] = o;
  cursor[i] = o;
}

__global__ void fill_kernel(const int* __restrict__ ei, int* __restrict__ cursor, int* __restrict__ csr){
  int e = blockIdx.x*256 + threadIdx.x;
  if (e >= ETOT) return;
  int src, dst;
  if (e < EE){ src = ei[e]; dst = ei[EE + e]; } else { src = e - EE; dst = e - EE; }
  int pos = atomicAdd(&cursor[dst], 1);
  csr[pos] = src;
}

// ---------------- fold weights into bf16, MFMA-fragment order ----------------
__global__ void build_wfrag(const float* __restrict__ bw, const float* __restrict__ sw,
                            const float* __restrict__ sc, unsigned short* __restrict__ wfrag){
  int idx = blockIdx.x*256 + threadIdx.x;
  if (idx >= 3*128*1024) return;
  int k = idx & 1023;
  int o = (idx >> 10) & 127;
  int l = idx >> 17;
  int i = k >> 3, f = k & 7;
  int oi = (l*DD + o)*DD + i;
  float w = (f == 0) ? bw[oi] : sw[oi*7 + (f-1)] * sc[oi];
  int s = k >> 6;
  int sl = (k >> 4) & 3, half = (k >> 3) & 1, j = k & 7;
  int ntile = o >> 5, n = o & 31;
  int dst = l*131072 + s*8192 + (((ntile*4 + sl)*64) + half*32 + n)*8 + j;
  wfrag[dst] = (unsigned short)f2bf(w);
}

// ---------------- fused KAN feats + GEMM + pack + attention logits ----------------
// 782 blocks x 256 thr (4 waves). Tile 64 rows x 128 cols; wave w = cols w*32..+31.
// Afrag double-buffered (1 barrier/stage). Epilogue: bf16-pack h -> hpack AND
// compute a_src/a_dst per (row, head) from the LDS h tile (replaces attlog kernel).
__global__ __launch_bounds__(256) void kan_gemm(const float* __restrict__ xin,
                                                const unsigned short* __restrict__ wfrag,
                                                const float* __restrict__ attS,
                                                const float* __restrict__ attD,
                                                unsigned int* __restrict__ hpack,
                                                float* __restrict__ asrc,
                                                float* __restrict__ adst, int layer)
{
  __shared__ __align__(16) float xs[64*132];            // 33 KB; reused as hs[64][136] ushort
  __shared__ __align__(16) unsigned short Afrag[2][4096]; // 2 x 8 KB
  const int t    = threadIdx.x;
  const int lane = t & 63;
  const int w    = t >> 6;
  const int half = lane >> 5;
  const int mn   = lane & 31;
  const int row0 = blockIdx.x * 64;
  const int r_my = t & 63;
  const int il0  = t >> 6;
  const unsigned short* wl = wfrag + layer*131072;

  // stage x tile (64 x 128 f32), coalesced float4
#pragma unroll
  for (int q=0;q<8;++q){
    int p = q*256 + t;
    int r = p >> 5, c4 = p & 31;
    int grow = row0 + r;
    float4 v = make_float4(0.f,0.f,0.f,0.f);
    if (grow < NN) v = *(const float4*)(xin + (size_t)grow*DD + c4*4);
    *(float4*)(&xs[r*132 + c4*4]) = v;
  }
  __syncthreads();

  float16_t acc[2];
#pragma unroll
  for (int i=0;i<16;++i){ acc[0][i]=0.f; acc[1][i]=0.f; }

  int4 Bc[4], Bn[4];
#pragma unroll
  for (int sl=0;sl<4;++sl)
    Bc[sl] = *(const int4*)(wl + ((w*4+sl)*64 + lane)*8);

  const int foa = (((r_my>>5)*8 + il0)*32 + (r_my&31))*8;
  const int fob = (((r_my>>5)*8 + il0+4)*32 + (r_my&31))*8;
  {
    int4 Pa = kan_feats_pack(xs[r_my*132 + il0]);
    int4 Pb = kan_feats_pack(xs[r_my*132 + il0 + 4]);
    *(int4*)(&Afrag[0][foa]) = Pa;
    *(int4*)(&Afrag[0][fob]) = Pb;
  }
  __syncthreads();

  for (int s=0; s<16; ++s){
    if (s < 15){
      const unsigned short* wsrc = wl + (s+1)*8192;
#pragma unroll
      for (int sl=0;sl<4;++sl)
        Bn[sl] = *(const int4*)(wsrc + ((w*4+sl)*64 + lane)*8);
      int4 Pa = kan_feats_pack(xs[r_my*132 + (s+1)*8 + il0]);
      int4 Pb = kan_feats_pack(xs[r_my*132 + (s+1)*8 + il0 + 4]);
      *(int4*)(&Afrag[(s+1)&1][foa]) = Pa;
      *(int4*)(&Afrag[(s+1)&1][fob]) = Pb;
    }
    const unsigned short* A = Afrag[s&1];
#pragma unroll
    for (int sl=0; sl<4; ++sl){
      int4 a0i = *(const int4*)(A + (((0*8 + sl*2 + half)*32) + mn)*8);
      int4 a1i = *(const int4*)(A + (((1*8 + sl*2 + half)*32) + mn)*8);
      bf16x8 b = __builtin_bit_cast(bf16x8, Bc[sl]);
      acc[0] = __builtin_amdgcn_mfma_f32_32x32x16_bf16(__builtin_bit_cast(bf16x8, a0i), b, acc[0], 0, 0, 0);
      acc[1] = __builtin_amdgcn_mfma_f32_32x32x16_bf16(__builtin_bit_cast(bf16x8, a1i), b, acc[1], 0, 0, 0);
    }
#pragma unroll
    for (int sl=0;sl<4;++sl) Bc[sl] = Bn[sl];
    __syncthreads();
  }

  // epilogue: acc -> bf16 -> LDS
  unsigned short* hs = (unsigned short*)xs;   // hs[64][136]
#pragma unroll
  for (int mt=0; mt<2; ++mt){
#pragma unroll
    for (int reg=0; reg<16; ++reg){
      int row = mt*32 + (reg&3) + 8*(reg>>2) + 4*half;
      int col = w*32 + mn;
      hs[row*136 + col] = (unsigned short)f2bf(acc[mt][reg]);
    }
  }
  __syncthreads();
  // packed h store
#pragma unroll
  for (int q=0;q<4;++q){
    int p = q*256 + t;
    int row = p >> 4, u4 = p & 15;
    uint4 v = *(const uint4*)((const unsigned int*)(hs + row*136) + u4*4);
    int grow = row0 + row;
    if (grow < NN) *(uint4*)(hpack + (size_t)grow*64 + u4*4) = v;
  }
  // fused attention logits: thread = (row r, head h)
  {
    int r = t >> 2, h = t & 3;
    const unsigned* hrow = (const unsigned*)(hs + r*136) + h*16;
    const float* ws = attS + (layer*4 + h)*32;
    const float* wd = attD + (layer*4 + h)*32;
    float ss = 0.f, sd = 0.f;
#pragma unroll
    for (int j=0;j<16;++j){
      unsigned u = hrow[j];
      float flo = __uint_as_float(u << 16);
      float fhi = __uint_as_float(u & 0xffff0000u);
      ss += flo*ws[2*j] + fhi*ws[2*j+1];
      sd += flo*wd[2*j] + fhi*wd[2*j+1];
    }
    int grow = row0 + r;
    if (grow < NN){ asrc[grow*4 + h] = ss; adst[grow*4 + h] = sd; }
  }
}

// ---------------- GAT aggregation v3: register-resident edges, batched gathers ----------------
// One wave per dst node. Softmax lanes: eL = lane>>2, h = lane&3; up to 64 edges
// held in registers (4 chunks of 16); csr/asrc read ONCE. Channel pass issues 16
// independent hpack loads per chunk before consuming. d>64 handled by streaming tail.
__global__ __launch_bounds__(256) void attn_kernel(
    const unsigned int* __restrict__ hpack, const float* __restrict__ asrc, const float* __restrict__ adst,
    const int* __restrict__ offs, const int* __restrict__ deg, const int* __restrict__ csr,
    const float* __restrict__ bias, float* __restrict__ hout, int layer)
{
  const int wave = threadIdx.x >> 6;
  const int lane = threadIdx.x & 63;
  const int n = blockIdx.x*4 + wave;
  if (n >= NN) return;
  const int st = offs[n];
  const int d  = deg[n];
  const int eL = lane >> 2, h = lane & 3;
  const float adh = adst[n*4 + h];

  int   srcv[4];
  float ev[4];
  float mL = -3.4e38f;
#pragma unroll
  for (int c=0;c<4;++c){
    srcv[c] = 0; ev[c] = -3.4e38f;
    int e = c*16 + eL;
    if (e < d){
      int s2 = csr[st + e];
      srcv[c] = s2;
      float e0 = asrc[s2*4 + h] + adh;
      ev[c] = (e0 > 0.f) ? e0 : 0.2f*e0;
      mL = fmaxf(mL, ev[c]);
    }
  }
  for (int c=64; c<d; c+=16){            // rare tail
    int e = c + eL;
    if (e < d){
      int s2 = csr[st + e];
      float e0 = asrc[s2*4 + h] + adh;
      float evv = (e0 > 0.f) ? e0 : 0.2f*e0;
      mL = fmaxf(mL, evv);
    }
  }
#pragma unroll
  for (int o=4;o<64;o<<=1) mL = fmaxf(mL, __shfl_xor(mL, o));

  float av4[4];
  float sL = 0.f;
#pragma unroll
  for (int c=0;c<4;++c){ av4[c] = __expf(ev[c] - mL); sL += av4[c]; }
  for (int c=64; c<d; c+=16){            // rare tail
    int e = c + eL;
    if (e < d){
      int s2 = csr[st + e];
      float e0 = asrc[s2*4 + h] + adh;
      float evv = (e0 > 0.f) ? e0 : 0.2f*e0;
      sL += __expf(evv - mL);
    }
  }
#pragma unroll
  for (int o=4;o<64;o<<=1) sL += __shfl_xor(sL, o);
  const float inv = 1.f/(sL + 1e-16f);

  const int hq = lane >> 4;
  float accL = 0.f, accH = 0.f;
#pragma unroll
  for (int c=0;c<4;++c){
    if (c*16 < d){                       // wave-uniform
      float ac = av4[c] * inv;
      int lim = d - c*16; if (lim > 16) lim = 16;
      unsigned uv[16]; float aj[16];
#pragma unroll
      for (int j=0;j<16;++j){
        int sj = __shfl(srcv[c], j*4);
        aj[j]  = __shfl(ac,      j*4 + hq);
        if (j < lim) uv[j] = hpack[(size_t)sj*64 + lane];
        else         uv[j] = 0u;
      }
#pragma unroll
      for (int j=0;j<16;++j){
        accL = fmaf(aj[j], __uint_as_float(uv[j] << 16),         accL);
        accH = fmaf(aj[j], __uint_as_float(uv[j] & 0xffff0000u), accH);
      }
    }
  }
  for (int c=64; c<d; c+=16){            // rare tail
    int e = c + eL;
    int s2 = 0; float al = 0.f;
    if (e < d){
      s2 = csr[st + e];
      float e0 = asrc[s2*4 + h] + adh;
      float evv = (e0 > 0.f) ? e0 : 0.2f*e0;
      al = __expf(evv - mL) * inv;
    }
    int lim = d - c; if (lim > 16) lim = 16;
    for (int j=0;j<lim;++j){
      int sj = __shfl(s2, j*4);
      float aH = __shfl(al, j*4 + hq);
      unsigned u = hpack[(size_t)sj*64 + lane];
      accL = fmaf(aH, __uint_as_float(u << 16),         accL);
      accH = fmaf(aH, __uint_as_float(u & 0xffff0000u), accH);
    }
  }
  float2 bv = *(const float2*)(bias + layer*DD + 2*lane);
  float o0 = siluf(accL + bv.x);
  float o1 = siluf(accH + bv.y);
  *(float2*)(hout + (size_t)n*DD + 2*lane) = make_float2(o0, o1);
}

// ---------------- global_add_pool (batch is sorted) ----------------
__global__ __launch_bounds__(128) void pool_kernel(const float* __restrict__ h,
    const int* __restrict__ batch, float* __restrict__ pooled)
{
  int c = threadIdx.x;
  int n0 = blockIdx.x*128;
  float sum = 0.f; int cur = -1;
  for (int r=0;r<128;++r){
    int n = n0 + r;
    if (n >= NN) break;
    int g = batch[n];
    if (g != cur){
      if (cur >= 0) atomicAdd(&pooled[cur*DD + c], sum);
      cur = g; sum = 0.f;
    }
    sum += h[n*DD + c];
  }
  if (cur >= 0) atomicAdd(&pooled[cur*DD + c], sum);
}

// ---------------- KAN readout + log_softmax (1 block per graph) ----------------
__global__ __launch_bounds__(64) void readout_kernel(const float* __restrict__ pooled,
    const float* __restrict__ bw, const float* __restrict__ sw, const float* __restrict__ sc,
    float* __restrict__ out)
{
  int g = blockIdx.x, lane = threadIdx.x;
  float xa = pooled[g*DD + lane];
  float xb = pooled[g*DD + lane + 64];
  float fa[8], fb[8];
  kan_feats(xa, fa);
  kan_feats(xb, fb);
  float logits[NCL];
#pragma unroll
  for (int c=0;c<NCL;++c){
    int ia = c*DD + lane, ib = ia + 64;
    float sca = sc[ia], scb = sc[ib];
    float p = fa[0]*bw[ia] + fb[0]*bw[ib];
#pragma unroll
    for (int f=1;f<8;++f)
      p += fa[f]*sw[ia*7 + f-1]*sca + fb[f]*sw[ib*7 + f-1]*scb;
#pragma unroll
    for (int o=1;o<64;o<<=1) p += __shfl_xor(p, o);
    logits[c] = p;
  }
  float mx = logits[0];
#pragma unroll
  for (int c=1;c<NCL;++c) mx = fmaxf(mx, logits[c]);
  float lse = 0.f;
#pragma unroll
  for (int c=0;c<NCL;++c) lse += __expf(logits[c]-mx);
  lse = mx + logf(lse);
  if (lane < NCL){
    float v = 0.f;
#pragma unroll
    for (int c=0;c<NCL;++c) if (lane == c) v = logits[c] - lse;
    out[g*NCL + lane] = v;
  }
}

// ---------------- host ----------------
extern "C" void kernel_launch(void* const* d_in, const int* in_sizes, int n_in,
                              void* d_out, int out_size, void* d_ws, size_t ws_size,
                              hipStream_t stream)
{
  const float* x        = (const float*)d_in[0];
  const int*   ei       = (const int*)  d_in[1];
  const int*   batch    = (const int*)  d_in[2];
  const float* base_w   = (const float*)d_in[3];
  const float* spline_w = (const float*)d_in[4];
  const float* scaler   = (const float*)d_in[5];
  const float* att_src  = (const float*)d_in[6];
  const float* att_dst  = (const float*)d_in[7];
  const float* bias     = (const float*)d_in[8];
  const float* ro_bw    = (const float*)d_in[9];
  const float* ro_sw    = (const float*)d_in[10];
  const float* ro_sc    = (const float*)d_in[11];
  float* out = (float*)d_out;

  char* p = (char*)d_ws;
  auto alloc = [&](size_t bytes)->char* {
    char* r = p;
    p += (bytes + 255) & ~(size_t)255;
    return r;
  };
  unsigned int* hpack = (unsigned int*)alloc((size_t)50048*64*4);
  float* hbuf   = (float*)alloc((size_t)NN*DD*4);
  unsigned short* wfrag = (unsigned short*)alloc((size_t)3*131072*2);
  float* asrc   = (float*)alloc((size_t)NN*4*4);
  float* adst   = (float*)alloc((size_t)NN*4*4);
  float* pooled = (float*)alloc((size_t)NGR*DD*4);
  int*   deg    = (int*)alloc((size_t)NN*4);
  int*   offs   = (int*)alloc((size_t)NN*4);
  int*   cursor = (int*)alloc((size_t)NN*4);
  int*   csr    = (int*)alloc((size_t)ETOT*4);
  int*   part   = (int*)alloc((size_t)256*4);

  const int nbs = (NN + 255)/256;
  hipMemsetAsync(deg, 0, (size_t)NN*sizeof(int), stream);
  hist_kernel <<<(ETOT+255)/256, 256, 0, stream>>>(ei, deg);
  scan1_kernel<<<nbs, 256, 0, stream>>>(deg, offs, part);
  scan2_kernel<<<1,   256, 0, stream>>>(part, nbs);
  scan3_kernel<<<nbs, 256, 0, stream>>>(offs, part, cursor);
  fill_kernel <<<(ETOT+255)/256, 256, 0, stream>>>(ei, cursor, csr);
  build_wfrag <<<(3*128*1024)/256, 256, 0, stream>>>(base_w, spline_w, scaler, wfrag);

  const float* cur = x;
  for (int l=0; l<3; ++l){
    kan_gemm   <<<(NN+63)/64, 256, 0, stream>>>(cur, wfrag, att_src, att_dst,
                                                hpack, asrc, adst, l);
    attn_kernel<<<(NN+3)/4,   256, 0, stream>>>(hpack, asrc, adst, offs, deg, csr,
                                                bias, hbuf, l);
    cur = hbuf;
  }
  hipMemsetAsync(pooled, 0, (size_t)NGR*DD*sizeof(float), stream);
  pool_kernel   <<<(NN+127)/128, 128, 0, stream>>>(hbuf, batch, pooled);
  readout_kernel<<<NGR, 64, 0, stream>>>(pooled, ro_bw, ro_sw, ro_sc, out);
}

// Round 7
// 488.514 us; speedup vs baseline: 2.6118x; 1.0111x over previous
//
#include <hip/hip_runtime.h>
#include <math.h>

#define NN 50000
#define EE 800000
#define ETOT (EE + NN)
#define NGR 64
#define DD 128
#define NCL 10

typedef __attribute__((ext_vector_type(16))) float float16_t;
typedef __attribute__((ext_vector_type(8)))  __bf16 bf16x8;

// ---------------- device helpers ----------------
__device__ __forceinline__ float siluf(float x){ return x / (1.f + __expf(-x)); }

__device__ __forceinline__ unsigned f2bf(float f){
  union { float f; unsigned u; } v; v.f = f;
  unsigned r = v.u + 0x7fffu + ((v.u >> 16) & 1u);
  return (r >> 16) & 0xffffu;
}

// 8 KAN features of scalar x: [silu(x), B0..B6] (float version for readout)
__device__ __forceinline__ void kan_feats(float x, float* f8){
  f8[0] = siluf(x);
  float u = 2.f*x + 5.f;
  int cell = -1;
  float n0=0.f,n1=0.f,n2=0.f,n3=0.f;
  if (u >= 0.f && u < 10.f){
    cell = (int)u;
    float t = u - (float)cell;
    float t2 = t*t, t3 = t2*t;
    float omt = 1.f - t;
    const float s6 = 1.f/6.f;
    n0 = t3*s6;
    n1 = s6*(1.f + 3.f*t + 3.f*t2 - 3.f*t3);
    n2 = s6*(4.f - 6.f*t2 + 3.f*t3);
    n3 = omt*omt*omt*s6;
  }
#pragma unroll
  for (int j=0;j<7;++j){
    int k = cell - j;
    float v = (k==0)?n0:((k==1)?n1:((k==2)?n2:((k==3)?n3:0.f)));
    f8[1+j] = v;
  }
}

// Packed bf16 A-fragment of scalar x: us[0..7] = [silu, B0..B6] via 64-bit shift.
__device__ __forceinline__ int4 kan_feats_pack(float x){
  unsigned sbf = f2bf(siluf(x));
  float u = 2.f*x + 5.f;
  bool valid = (u >= 0.f) && (u < 10.f);
  float uc = valid ? u : 0.f;
  int cell = (int)uc;
  float t = uc - (float)cell;
  float t2 = t*t, t3 = t2*t, omt = 1.f - t;
  const float s6 = 1.f/6.f;
  float n0 = t3*s6;
  float n1 = s6*(1.f + 3.f*t + 3.f*t2 - 3.f*t3);
  float n2 = s6*(4.f - 6.f*t2 + 3.f*t3);
  float n3 = omt*omt*omt*s6;
  unsigned p0=f2bf(n0), p1=f2bf(n1), p2=f2bf(n2), p3=f2bf(n3);
  unsigned long long P = ((unsigned long long)(p1 | (p0<<16)) << 32)
                       |  (unsigned long long)(p3 | (p2<<16));
  int sh = cell*16 - 48;
  unsigned long long shl    = P << (sh & 63);
  unsigned long long shrhi  = P >> ((64 - sh) & 63);
  unsigned long long shllo2 = P << ((sh - 64) & 63);
  unsigned long long shrlo  = P >> ((-sh) & 63);
  unsigned long long F0, F1;
  if (sh < 0)       { F0 = shrlo; F1 = 0ull; }
  else if (sh < 64) { F0 = shl;   F1 = (sh==0)? 0ull : shrhi; }
  else              { F0 = 0ull;  F1 = shllo2; }
  if (!valid){ F0 = 0ull; F1 = 0ull; }
  unsigned w0 = ((unsigned)(F0 & 0xffffull) << 16) | sbf;
  unsigned w1 = (unsigned)((F0 >> 16) & 0xffffffffull);
  unsigned w2 = (unsigned)((F0 >> 48) & 0xffffull) | (((unsigned)(F1 & 0xffffull)) << 16);
  unsigned w3 = (unsigned)((F1 >> 16) & 0xffffffffull);
  return make_int4((int)w0,(int)w1,(int)w2,(int)w3);
}

// ---------------- CSR build (dst-indexed) ----------------
__global__ void hist_kernel(const int* __restrict__ ei, int* __restrict__ deg){
  int e = blockIdx.x*256 + threadIdx.x;
  if (e >= ETOT) return;
  int dst = (e < EE) ? ei[EE + e] : (e - EE);
  atomicAdd(&deg[dst], 1);
}

__global__ void scan1_kernel(const int* __restrict__ deg, int* __restrict__ offs, int* __restrict__ part){
  __shared__ int sh[256];
  int tid = threadIdx.x;
  int i = blockIdx.x*256 + tid;
  int v = (i < NN) ? deg[i] : 0;
  sh[tid] = v; __syncthreads();
  for (int o=1;o<256;o<<=1){
    int t2 = (tid >= o) ? sh[tid - o] : 0;
    __syncthreads();
    sh[tid] += t2;
    __syncthreads();
  }
  int incl = sh[tid];
  if (i < NN) offs[i] = incl - v;
  if (tid == 255) part[blockIdx.x] = incl;
}

__global__ void scan2_kernel(int* __restrict__ part, int nb){
  __shared__ int sh[256];
  int tid = threadIdx.x;
  int v = (tid < nb) ? part[tid] : 0;
  sh[tid] = v; __syncthreads();
  for (int o=1;o<256;o<<=1){
    int t2 = (tid >= o) ? sh[tid - o] : 0;
    __syncthreads();
    sh[tid] += t2;
    __syncthreads();
  }
  if (tid < nb) part[tid] = sh[tid] - v;
}

__global__ void scan3_kernel(int* __restrict__ offs, const int* __restrict__ part, int* __restrict__ cursor){
  int i = blockIdx.x*256 + threadIdx.x;
  if (i >= NN) return;
  int o = offs[i] + part[blockIdx.x];
  offs[i] = o;
  cursor[i] = o;
}

// Multi-pass fill: pass p commits only dst in [p*8192, (p+1)*8192) so the live
// csr region (~560 KB) stays L2-resident and 64B lines absorb ~16 entries
// before write-back (was: 850k scattered 4B writes -> 55 MB of line evictions).
__global__ __launch_bounds__(256) void fill_kernel(const int* __restrict__ ei,
                                                   int* __restrict__ cursor,
                                                   int* __restrict__ csr){
  int e = blockIdx.x*256 + threadIdx.x;
  int src = 0, myp = -1, dst = -1;
  if (e < ETOT){
    if (e < EE){ src = ei[e]; dst = ei[EE + e]; } else { src = e - EE; dst = e - EE; }
    myp = dst >> 13;            // 7 ranges cover 0..57343 >= NN
  }
#pragma unroll 1
  for (int pass=0; pass<7; ++pass){
    if (myp == pass){
      int pos = atomicAdd(&cursor[dst], 1);
      csr[pos] = src;
    }
    __syncthreads();            // keep block's waves pass-aligned
  }
}

// ---------------- fold weights into bf16, MFMA-fragment order ----------------
__global__ void build_wfrag(const float* __restrict__ bw, const float* __restrict__ sw,
                            const float* __restrict__ sc, unsigned short* __restrict__ wfrag){
  int idx = blockIdx.x*256 + threadIdx.x;
  if (idx >= 3*128*1024) return;
  int k = idx & 1023;
  int o = (idx >> 10) & 127;
  int l = idx >> 17;
  int i = k >> 3, f = k & 7;
  int oi = (l*DD + o)*DD + i;
  float w = (f == 0) ? bw[oi] : sw[oi*7 + (f-1)] * sc[oi];
  int s = k >> 6;
  int sl = (k >> 4) & 3, half = (k >> 3) & 1, j = k & 7;
  int ntile = o >> 5, n = o & 31;
  int dst = l*131072 + s*8192 + (((ntile*4 + sl)*64) + half*32 + n)*8 + j;
  wfrag[dst] = (unsigned short)f2bf(w);
}

// ---------------- fused KAN feats + GEMM + pack + attention logits ----------------
__global__ __launch_bounds__(256) void kan_gemm(const float* __restrict__ xin,
                                                const unsigned short* __restrict__ wfrag,
                                                const float* __restrict__ attS,
                                                const float* __restrict__ attD,
                                                unsigned int* __restrict__ hpack,
                                                float* __restrict__ asrc,
                                                float* __restrict__ adst, int layer)
{
  __shared__ __align__(16) float xs[64*132];
  __shared__ __align__(16) unsigned short Afrag[2][4096];
  const int t    = threadIdx.x;
  const int lane = t & 63;
  const int w    = t >> 6;
  const int half = lane >> 5;
  const int mn   = lane & 31;
  const int row0 = blockIdx.x * 64;
  const int r_my = t & 63;
  const int il0  = t >> 6;
  const unsigned short* wl = wfrag + layer*131072;

#pragma unroll
  for (int q=0;q<8;++q){
    int p = q*256 + t;
    int r = p >> 5, c4 = p & 31;
    int grow = row0 + r;
    float4 v = make_float4(0.f,0.f,0.f,0.f);
    if (grow < NN) v = *(const float4*)(xin + (size_t)grow*DD + c4*4);
    *(float4*)(&xs[r*132 + c4*4]) = v;
  }
  __syncthreads();

  float16_t acc[2];
#pragma unroll
  for (int i=0;i<16;++i){ acc[0][i]=0.f; acc[1][i]=0.f; }

  int4 Bc[4], Bn[4];
#pragma unroll
  for (int sl=0;sl<4;++sl)
    Bc[sl] = *(const int4*)(wl + ((w*4+sl)*64 + lane)*8);

  const int foa = (((r_my>>5)*8 + il0)*32 + (r_my&31))*8;
  const int fob = (((r_my>>5)*8 + il0+4)*32 + (r_my&31))*8;
  {
    int4 Pa = kan_feats_pack(xs[r_my*132 + il0]);
    int4 Pb = kan_feats_pack(xs[r_my*132 + il0 + 4]);
    *(int4*)(&Afrag[0][foa]) = Pa;
    *(int4*)(&Afrag[0][fob]) = Pb;
  }
  __syncthreads();

  for (int s=0; s<16; ++s){
    if (s < 15){
      const unsigned short* wsrc = wl + (s+1)*8192;
#pragma unroll
      for (int sl=0;sl<4;++sl)
        Bn[sl] = *(const int4*)(wsrc + ((w*4+sl)*64 + lane)*8);
      int4 Pa = kan_feats_pack(xs[r_my*132 + (s+1)*8 + il0]);
      int4 Pb = kan_feats_pack(xs[r_my*132 + (s+1)*8 + il0 + 4]);
      *(int4*)(&Afrag[(s+1)&1][foa]) = Pa;
      *(int4*)(&Afrag[(s+1)&1][fob]) = Pb;
    }
    const unsigned short* A = Afrag[s&1];
#pragma unroll
    for (int sl=0; sl<4; ++sl){
      int4 a0i = *(const int4*)(A + (((0*8 + sl*2 + half)*32) + mn)*8);
      int4 a1i = *(const int4*)(A + (((1*8 + sl*2 + half)*32) + mn)*8);
      bf16x8 b = __builtin_bit_cast(bf16x8, Bc[sl]);
      acc[0] = __builtin_amdgcn_mfma_f32_32x32x16_bf16(__builtin_bit_cast(bf16x8, a0i), b, acc[0], 0, 0, 0);
      acc[1] = __builtin_amdgcn_mfma_f32_32x32x16_bf16(__builtin_bit_cast(bf16x8, a1i), b, acc[1], 0, 0, 0);
    }
#pragma unroll
    for (int sl=0;sl<4;++sl) Bc[sl] = Bn[sl];
    __syncthreads();
  }

  unsigned short* hs = (unsigned short*)xs;
#pragma unroll
  for (int mt=0; mt<2; ++mt){
#pragma unroll
    for (int reg=0; reg<16; ++reg){
      int row = mt*32 + (reg&3) + 8*(reg>>2) + 4*half;
      int col = w*32 + mn;
      hs[row*136 + col] = (unsigned short)f2bf(acc[mt][reg]);
    }
  }
  __syncthreads();
#pragma unroll
  for (int q=0;q<4;++q){
    int p = q*256 + t;
    int row = p >> 4, u4 = p & 15;
    uint4 v = *(const uint4*)((const unsigned int*)(hs + row*136) + u4*4);
    int grow = row0 + row;
    if (grow < NN) *(uint4*)(hpack + (size_t)grow*64 + u4*4) = v;
  }
  {
    int r = t >> 2, h = t & 3;
    const unsigned* hrow = (const unsigned*)(hs + r*136) + h*16;
    const float* ws = attS + (layer*4 + h)*32;
    const float* wd = attD + (layer*4 + h)*32;
    float ss = 0.f, sd = 0.f;
#pragma unroll
    for (int j=0;j<16;++j){
      unsigned u = hrow[j];
      float flo = __uint_as_float(u << 16);
      float fhi = __uint_as_float(u & 0xffff0000u);
      ss += flo*ws[2*j] + fhi*ws[2*j+1];
      sd += flo*wd[2*j] + fhi*wd[2*j+1];
    }
    int grow = row0 + r;
    if (grow < NN){ asrc[grow*4 + h] = ss; adst[grow*4 + h] = sd; }
  }
}

// ---------------- GAT aggregation v3: register-resident edges, batched gathers ----------------
__global__ __launch_bounds__(256) void attn_kernel(
    const unsigned int* __restrict__ hpack, const float* __restrict__ asrc, const float* __restrict__ adst,
    const int* __restrict__ offs, const int* __restrict__ deg, const int* __restrict__ csr,
    const float* __restrict__ bias, float* __restrict__ hout, int layer)
{
  const int wave = threadIdx.x >> 6;
  const int lane = threadIdx.x & 63;
  const int n = blockIdx.x*4 + wave;
  if (n >= NN) return;
  const int st = offs[n];
  const int d  = deg[n];
  const int eL = lane >> 2, h = lane & 3;
  const float adh = adst[n*4 + h];

  int   srcv[4];
  float ev[4];
  float mL = -3.4e38f;
#pragma unroll
  for (int c=0;c<4;++c){
    srcv[c] = 0; ev[c] = -3.4e38f;
    int e = c*16 + eL;
    if (e < d){
      int s2 = csr[st + e];
      srcv[c] = s2;
      float e0 = asrc[s2*4 + h] + adh;
      ev[c] = (e0 > 0.f) ? e0 : 0.2f*e0;
      mL = fmaxf(mL, ev[c]);
    }
  }
  for (int c=64; c<d; c+=16){
    int e = c + eL;
    if (e < d){
      int s2 = csr[st + e];
      float e0 = asrc[s2*4 + h] + adh;
      float evv = (e0 > 0.f) ? e0 : 0.2f*e0;
      mL = fmaxf(mL, evv);
    }
  }
#pragma unroll
  for (int o=4;o<64;o<<=1) mL = fmaxf(mL, __shfl_xor(mL, o));

  float av4[4];
  float sL = 0.f;
#pragma unroll
  for (int c=0;c<4;++c){ av4[c] = __expf(ev[c] - mL); sL += av4[c]; }
  for (int c=64; c<d; c+=16){
    int e = c + eL;
    if (e < d){
      int s2 = csr[st + e];
      float e0 = asrc[s2*4 + h] + adh;
      float evv = (e0 > 0.f) ? e0 : 0.2f*e0;
      sL += __expf(evv - mL);
    }
  }
#pragma unroll
  for (int o=4;o<64;o<<=1) sL += __shfl_xor(sL, o);
  const float inv = 1.f/(sL + 1e-16f);

  const int hq = lane >> 4;
  float accL = 0.f, accH = 0.f;
#pragma unroll
  for (int c=0;c<4;++c){
    if (c*16 < d){
      float ac = av4[c] * inv;
      int lim = d - c*16; if (lim > 16) lim = 16;
      unsigned uv[16]; float aj[16];
#pragma unroll
      for (int j=0;j<16;++j){
        int sj = __shfl(srcv[c], j*4);
        aj[j]  = __shfl(ac,      j*4 + hq);
        if (j < lim) uv[j] = hpack[(size_t)sj*64 + lane];
        else         uv[j] = 0u;
      }
#pragma unroll
      for (int j=0;j<16;++j){
        accL = fmaf(aj[j], __uint_as_float(uv[j] << 16),         accL);
        accH = fmaf(aj[j], __uint_as_float(uv[j] & 0xffff0000u), accH);
      }
    }
  }
  for (int c=64; c<d; c+=16){
    int e = c + eL;
    int s2 = 0; float al = 0.f;
    if (e < d){
      s2 = csr[st + e];
      float e0 = asrc[s2*4 + h] + adh;
      float evv = (e0 > 0.f) ? e0 : 0.2f*e0;
      al = __expf(evv - mL) * inv;
    }
    int lim = d - c; if (lim > 16) lim = 16;
    for (int j=0;j<lim;++j){
      int sj = __shfl(s2, j*4);
      float aH = __shfl(al, j*4 + hq);
      unsigned u = hpack[(size_t)sj*64 + lane];
      accL = fmaf(aH, __uint_as_float(u << 16),         accL);
      accH = fmaf(aH, __uint_as_float(u & 0xffff0000u), accH);
    }
  }
  float2 bv = *(const float2*)(bias + layer*DD + 2*lane);
  float o0 = siluf(accL + bv.x);
  float o1 = siluf(accH + bv.y);
  *(float2*)(hout + (size_t)n*DD + 2*lane) = make_float2(o0, o1);
}

// ---------------- global_add_pool (batch is sorted) ----------------
__global__ __launch_bounds__(128) void pool_kernel(const float* __restrict__ h,
    const int* __restrict__ batch, float* __restrict__ pooled)
{
  int c = threadIdx.x;
  int n0 = blockIdx.x*128;
  float sum = 0.f; int cur = -1;
  for (int r=0;r<128;++r){
    int n = n0 + r;
    if (n >= NN) break;
    int g = batch[n];
    if (g != cur){
      if (cur >= 0) atomicAdd(&pooled[cur*DD + c], sum);
      cur = g; sum = 0.f;
    }
    sum += h[n*DD + c];
  }
  if (cur >= 0) atomicAdd(&pooled[cur*DD + c], sum);
}

// ---------------- KAN readout + log_softmax (1 block per graph) ----------------
__global__ __launch_bounds__(64) void readout_kernel(const float* __restrict__ pooled,
    const float* __restrict__ bw, const float* __restrict__ sw, const float* __restrict__ sc,
    float* __restrict__ out)
{
  int g = blockIdx.x, lane = threadIdx.x;
  float xa = pooled[g*DD + lane];
  float xb = pooled[g*DD + lane + 64];
  float fa[8], fb[8];
  kan_feats(xa, fa);
  kan_feats(xb, fb);
  float logits[NCL];
#pragma unroll
  for (int c=0;c<NCL;++c){
    int ia = c*DD + lane, ib = ia + 64;
    float sca = sc[ia], scb = sc[ib];
    float p = fa[0]*bw[ia] + fb[0]*bw[ib];
#pragma unroll
    for (int f=1;f<8;++f)
      p += fa[f]*sw[ia*7 + f-1]*sca + fb[f]*sw[ib*7 + f-1]*scb;
#pragma unroll
    for (int o=1;o<64;o<<=1) p += __shfl_xor(p, o);
    logits[c] = p;
  }
  float mx = logits[0];
#pragma unroll
  for (int c=1;c<NCL;++c) mx = fmaxf(mx, logits[c]);
  float lse = 0.f;
#pragma unroll
  for (int c=0;c<NCL;++c) lse += __expf(logits[c]-mx);
  lse = mx + logf(lse);
  if (lane < NCL){
    float v = 0.f;
#pragma unroll
    for (int c=0;c<NCL;++c) if (lane == c) v = logits[c] - lse;
    out[g*NCL + lane] = v;
  }
}

// ---------------- host ----------------
extern "C" void kernel_launch(void* const* d_in, const int* in_sizes, int n_in,
                              void* d_out, int out_size, void* d_ws, size_t ws_size,
                              hipStream_t stream)
{
  const float* x        = (const float*)d_in[0];
  const int*   ei       = (const int*)  d_in[1];
  const int*   batch    = (const int*)  d_in[2];
  const float* base_w   = (const float*)d_in[3];
  const float* spline_w = (const float*)d_in[4];
  const float* scaler   = (const float*)d_in[5];
  const float* att_src  = (const float*)d_in[6];
  const float* att_dst  = (const float*)d_in[7];
  const float* bias     = (const float*)d_in[8];
  const float* ro_bw    = (const float*)d_in[9];
  const float* ro_sw    = (const float*)d_in[10];
  const float* ro_sc    = (const float*)d_in[11];
  float* out = (float*)d_out;

  char* p = (char*)d_ws;
  auto alloc = [&](size_t bytes)->char* {
    char* r = p;
    p += (bytes + 255) & ~(size_t)255;
    return r;
  };
  unsigned int* hpack = (unsigned int*)alloc((size_t)50048*64*4);
  float* hbuf   = (float*)alloc((size_t)NN*DD*4);
  unsigned short* wfrag = (unsigned short*)alloc((size_t)3*131072*2);
  float* asrc   = (float*)alloc((size_t)NN*4*4);
  float* adst   = (float*)alloc((size_t)NN*4*4);
  float* pooled = (float*)alloc((size_t)NGR*DD*4);
  int*   deg    = (int*)alloc((size_t)NN*4);
  int*   offs   = (int*)alloc((size_t)NN*4);
  int*   cursor = (int*)alloc((size_t)NN*4);
  int*   csr    = (int*)alloc((size_t)ETOT*4);
  int*   part   = (int*)alloc((size_t)256*4);

  const int nbs = (NN + 255)/256;
  hipMemsetAsync(deg, 0, (size_t)NN*sizeof(int), stream);
  hist_kernel <<<(ETOT+255)/256, 256, 0, stream>>>(ei, deg);
  scan1_kernel<<<nbs, 256, 0, stream>>>(deg, offs, part);
  scan2_kernel<<<1,   256, 0, stream>>>(part, nbs);
  scan3_kernel<<<nbs, 256, 0, stream>>>(offs, part, cursor);
  fill_kernel <<<(ETOT+255)/256, 256, 0, stream>>>(ei, cursor, csr);
  build_wfrag <<<(3*128*1024)/256, 256, 0, stream>>>(base_w, spline_w, scaler, wfrag);

  const float* cur = x;
  for (int l=0; l<3; ++l){
    kan_gemm   <<<(NN+63)/64, 256, 0, stream>>>(cur, wfrag, att_src, att_dst,
                                                hpack, asrc, adst, l);
    attn_kernel<<<(NN+3)/4,   256, 0, stream>>>(hpack, asrc, adst, offs, deg, csr,
                                                bias, hbuf, l);
    cur = hbuf;
  }
  hipMemsetAsync(pooled, 0, (size_t)NGR*DD*sizeof(float), stream);
  pool_kernel   <<<(NN+127)/128, 128, 0, stream>>>(hbuf, batch, pooled);
  readout_kernel<<<NGR, 64, 0, stream>>>(pooled, ro_bw, ro_sw, ro_sc, out);
}